// Round 3
// baseline (200.084 us; speedup 1.0000x reference)
//
#include <hip/hip_runtime.h>
#include <hip/hip_bf16.h>
#include <math.h>

#define NH 12
#define HD 64
#define NSEQ 1024
#define DMODEL 768
#define LOG2E 1.44269504f

typedef unsigned short ushort_t;
typedef float f32x4 __attribute__((ext_vector_type(4)));
typedef short bf16x8 __attribute__((ext_vector_type(8)));

__device__ __forceinline__ ushort_t f2bf(float f) {
    unsigned int u = __float_as_uint(f);
    u += 0x7FFFu + ((u >> 16) & 1u);   // RNE
    return (ushort_t)(u >> 16);
}

__device__ __forceinline__ unsigned pk2(float x, float y) {
    __hip_bfloat162 t = __float22bfloat162_rn(make_float2(x, y));
    union { __hip_bfloat162 b; unsigned u; } c; c.b = t;
    return c.u;
}

// async global->LDS DMA, 16B per lane; LDS dest = wave-uniform base + lane*16
__device__ __forceinline__ void gl_lds16(const ushort_t* g, ushort_t* l) {
    __builtin_amdgcn_global_load_lds(
        (const __attribute__((address_space(1))) unsigned int*)g,
        (__attribute__((address_space(3))) unsigned int*)l, 16, 0, 0);
}

// ---------------------------------------------------------------------------
// prep kernel: blocks [0,2688) convert x/qkv_w/proj_w fp32->bf16;
// blocks [2688, 6784) compute packed bias (bf16(elev*log2e)<<16 | bucket).
// ---------------------------------------------------------------------------
#define XB_N   3145728u
#define WQB_N  1769472u
#define PWB_N  589824u
#define CVT_BLOCKS 2688

__device__ __forceinline__ int bucketf(int rel) {
    const int n = -rel;
    const int u = (n < 0) ? 16 : 0;
    const int a = n < 0 ? -n : n;
    if (a < 8) return u + a;
    int v = 8 + (int)(log2f((float)a * 0.125f) * 2.0f + 1e-4f);
    if (v > 15) v = 15;
    return u + v;
}

__global__ __launch_bounds__(256) void prep_kernel(
    const float* __restrict__ x, const float* __restrict__ w1,
    const float* __restrict__ w2, ushort_t* __restrict__ dst,
    const float* __restrict__ coords, const float* __restrict__ elev,
    const float* __restrict__ alpha_p, unsigned* __restrict__ pack)
{
    const int t = threadIdx.x;
    if (blockIdx.x < CVT_BLOCKS) {
        const unsigned i = blockIdx.x * 256 + t;      // 8-elem chunk id
        const unsigned n0 = XB_N / 8, n1 = n0 + WQB_N / 8, n2 = n1 + PWB_N / 8;
        if (i >= n2) return;
        const float* src; unsigned off;
        if (i < n0)      { src = x;  off = i; }
        else if (i < n1) { src = w1; off = i - n0; }
        else             { src = w2; off = i - n1; }
        const float4 a = ((const float4*)src)[off * 2];
        const float4 b = ((const float4*)src)[off * 2 + 1];
        uint4 pk;
        pk.x = pk2(a.x, a.y); pk.y = pk2(a.z, a.w);
        pk.z = pk2(b.x, b.y); pk.w = pk2(b.z, b.w);
        ((uint4*)dst)[i] = pk;
    } else {
        const int blk = blockIdx.x - CVT_BLOCKS;
        const int b = blk >> 10, i = blk & 1023;
        const float alpha = alpha_p[0];
        const float2 ci = *(const float2*)&coords[(size_t)(b * NSEQ + i) * 2];
        const int cxi = (int)(ci.x * 128.0f), cyi = (int)(ci.y * 128.0f);
        const float ei = elev[b * NSEQ + i];
        const int j0 = t * 4;
        const float4 c01 = *(const float4*)&coords[(size_t)(b * NSEQ + j0) * 2];
        const float4 c23 = *(const float4*)&coords[(size_t)(b * NSEQ + j0 + 2) * 2];
        const float4 ej4 = *(const float4*)&elev[b * NSEQ + j0];
        const float cjx[4] = {c01.x, c01.z, c23.x, c23.z};
        const float cjy[4] = {c01.y, c01.w, c23.y, c23.w};
        const float ejv[4] = {ej4.x, ej4.y, ej4.z, ej4.w};
        unsigned r[4];
        #pragma unroll
        for (int k = 0; k < 4; ++k) {
            const int bx = bucketf(cxi - (int)(cjx[k] * 128.0f));
            const int by = bucketf(cyi - (int)(cjy[k] * 128.0f));
            const int idx = (bx << 5) + by;
            const float ed = (ejv[k] - ei) * 1e-3f;
            const float eb = fmaxf(-alpha * fmaxf(ed, 0.0f), -10.0f) * LOG2E;
            r[k] = ((unsigned)f2bf(eb) << 16) | (unsigned)idx;
        }
        uint4 o; o.x = r[0]; o.y = r[1]; o.z = r[2]; o.w = r[3];
        *(uint4*)&pack[((size_t)b << 20) + (size_t)i * NSEQ + j0] = o;
    }
}

// ---------------------------------------------------------------------------
// QKV GEMM (bf16 MFMA), 128M x 64N tiles -> grid 36x32 = 1152 blocks
// (4.5 blocks/CU). m97-style global_load_lds staging, LDS 12 KB.
// Whole block maps to exactly one of Q/K/V (64-col tile within one (s,h)).
// Q pre-scaled by 0.125*log2e; V transposed [bh][d][n].
// ---------------------------------------------------------------------------
__global__ __launch_bounds__(256) void qkv_gemm(
    const ushort_t* __restrict__ A, const ushort_t* __restrict__ B,
    const float* __restrict__ bias,
    ushort_t* __restrict__ Qb, ushort_t* __restrict__ Kb, ushort_t* __restrict__ Vtb)
{
    __shared__ __align__(16) ushort_t SM[6144];   // As [128*32], Bs [64*32]
    ushort_t* Asb = SM;
    ushort_t* Bsb = SM + 4096;
    const int t = threadIdx.x;
    const int lane = t & 63, w = t >> 6;
    const int wr = w >> 1, wc = w & 1;            // wave: 64 M-rows x 32 N-cols
    const int col = lane & 15, quad = lane >> 4;
    const int m0 = blockIdx.y * 128, c0 = blockIdx.x * 64;

    const f32x4 zero = {0.f, 0.f, 0.f, 0.f};
    f32x4 acc[4][2];
    #pragma unroll
    for (int i = 0; i < 4; ++i)
        #pragma unroll
        for (int j = 0; j < 2; ++j) acc[i][j] = zero;

    // staging: wave w stages A rows 32w..32w+31 (2 DMA) and B rows 16w..16w+15 (1 DMA)
    const int arow = w * 32 + (lane >> 2);
    const int brow = w * 16 + (lane >> 2);
    const int scol = (lane & 3) * 8;
    const ushort_t* Ag = A + (size_t)(m0 + arow) * DMODEL + scol;
    const ushort_t* Bg = B + (size_t)(c0 + brow) * DMODEL + scol;
    ushort_t* Asw = Asb + w * 32 * 32;
    ushort_t* Bsw = Bsb + w * 16 * 32;

    for (int k0 = 0; k0 < DMODEL; k0 += 32) {
        __syncthreads();
        gl_lds16(Ag + k0, Asw);
        gl_lds16(Ag + (size_t)16 * DMODEL + k0, Asw + 16 * 32);
        gl_lds16(Bg + k0, Bsw);
        __syncthreads();   // compiler drains vmcnt here
        bf16x8 af[4], bf[2];
        #pragma unroll
        for (int im = 0; im < 4; ++im)
            af[im] = *(const bf16x8*)&Asb[(wr * 64 + im * 16 + col) * 32 + quad * 8];
        #pragma unroll
        for (int jn = 0; jn < 2; ++jn)
            bf[jn] = *(const bf16x8*)&Bsb[(wc * 32 + jn * 16 + col) * 32 + quad * 8];
        #pragma unroll
        for (int im = 0; im < 4; ++im)
            #pragma unroll
            for (int jn = 0; jn < 2; ++jn)
                acc[im][jn] = __builtin_amdgcn_mfma_f32_16x16x32_bf16(af[im], bf[jn], acc[im][jn], 0, 0, 0);
    }

    const int s = c0 / DMODEL;                    // block-uniform
    const int h = (c0 % DMODEL) >> 6;
    const int b = m0 >> 10;
    const int bh = b * NH + h;
    const int n0 = (m0 & (NSEQ - 1)) + wr * 64;
    const int d0 = (c0 & 63);                     // 0 (tiles are h-aligned)
    const int cb = c0 + wc * 32;

    __syncthreads();   // retire all MFMA fragment reads before LDS reuse

    if (s < 2) {
        // LDS transpose epilogue: per im-block the wave writes a 16x32 bf16
        // tile (stride 40), reads rows back, stores one coalesced uint4/lane.
        ushort_t* lt = SM + w * 1280;             // 16 rows x 40
        ushort_t* dst = (s == 0) ? Qb : Kb;
        const float sc = (s == 0) ? 0.125f * LOG2E : 1.0f;
        float bv[2];
        #pragma unroll
        for (int jn = 0; jn < 2; ++jn) bv[jn] = bias[cb + jn * 16 + col];
        const int row16 = lane >> 2, seg = lane & 3;
        #pragma unroll
        for (int im = 0; im < 4; ++im) {
            #pragma unroll
            for (int jn = 0; jn < 2; ++jn) {
                const f32x4 a = acc[im][jn];
                #pragma unroll
                for (int r = 0; r < 4; ++r)
                    lt[(quad * 4 + r) * 40 + jn * 16 + col] = f2bf((a[r] + bv[jn]) * sc);
            }
            // same-wave DS is in-order: reads below see the writes above
            const uint4 u0 = *(const uint4*)&lt[row16 * 40 + seg * 8];
            const size_t gb = ((size_t)bh * NSEQ + n0 + im * 16 + row16) * HD
                            + wc * 32 + seg * 8;
            *(uint4*)&dst[gb] = u0;
        }
    } else {
        #pragma unroll
        for (int im = 0; im < 4; ++im) {
            #pragma unroll
            for (int jn = 0; jn < 2; ++jn) {
                const int d = wc * 32 + jn * 16 + col;
                const float bvv = bias[cb + jn * 16 + col];
                const f32x4 a = acc[im][jn];
                uint2 p;
                p.x = pk2(a[0] + bvv, a[1] + bvv);
                p.y = pk2(a[2] + bvv, a[3] + bvv);
                *(uint2*)&Vtb[((size_t)bh * HD + d) * NSEQ + n0 + im * 16 + quad * 4] = p;
            }
        }
    }
    (void)d0;
}

// ---------------------------------------------------------------------------
// Fused flash attention, R3: 512 threads / 8 waves, KV split 2-way inside the
// block. Waves 0-3 (group 0) do KV tiles 0-7; waves 4-7 (group 1) do tiles
// 8-15 over the SAME 64 q-rows. Fixed-m softmax => partials combine as pure
// sums: group 1 dumps f32 o_acc + l into dead K-staging LDS, group 0 adds,
// normalizes, stores. P redistribution in-register via permlane swaps.
// LDS 75776 B -> 2 blocks/CU x 8 waves = 16 waves/CU ceiling (was ~9).
// ---------------------------------------------------------------------------
__global__ __launch_bounds__(512) void attn_mfma(
    const ushort_t* __restrict__ Qb, const ushort_t* __restrict__ Kb,
    const ushort_t* __restrict__ Vtb,
    const unsigned* __restrict__ pack,
    const float* __restrict__ table,
    ushort_t* __restrict__ Ob)
{
    __shared__ __align__(16) ushort_t Ks[2][2][64 * 72];   // [group][buf]
    __shared__ __align__(16) ushort_t Vt[2][2][64 * 72];
    __shared__ ushort_t tabu[1024];   // bf16(table[:,h] * log2e)

    const int t = threadIdx.x;
    const int lane = t & 63, w = t >> 6;
    const int g = w >> 2, wg = w & 3;           // group, wave-in-group
    const int col = lane & 15, quad = lane >> 4;
    const int bid = blockIdx.x;
    const int it = bid & 15, bh = bid >> 4;
    const int h = bh % NH, b = bh / NH;
    const int i0 = it * 64;

    for (int i = t; i < 1024; i += 512)
        tabu[i] = f2bf(table[i * NH + h] * LOG2E);

    const ushort_t* Qg = Qb + ((size_t)bh * NSEQ + i0 + wg * 16 + col) * HD;
    const bf16x8 aq0 = *(const bf16x8*)(Qg + quad * 8);
    const bf16x8 aq1 = *(const bf16x8*)(Qg + 32 + quad * 8);

    const size_t kvbase = (size_t)bh * NSEQ * HD;
    const unsigned* prow = pack + ((size_t)b << 20)
                         + (size_t)(i0 + wg * 16 + col) * NSEQ + quad * 4;

    const int tg = t & 255;                     // thread-in-group
    const int srow = tg >> 3, sc8 = (tg & 7) * 8;
    const int so0 = srow * 72 + sc8;
    const int so1 = (srow + 32) * 72 + sc8;
    const int r0 = g * 512;                     // group's first kv row

    uint4 k0 = *(const uint4*)&Kb[kvbase + (size_t)(r0 + srow) * HD + sc8];
    uint4 k1 = *(const uint4*)&Kb[kvbase + (size_t)(r0 + srow + 32) * HD + sc8];
    uint4 v0 = *(const uint4*)&Vtb[kvbase + (size_t)srow * NSEQ + r0 + sc8];
    uint4 v1 = *(const uint4*)&Vtb[kvbase + (size_t)(srow + 32) * NSEQ + r0 + sc8];
    *(uint4*)&Ks[g][0][so0] = k0;
    *(uint4*)&Ks[g][0][so1] = k1;
    *(uint4*)&Vt[g][0][so0] = v0;
    *(uint4*)&Vt[g][0][so1] = v1;
    k0 = *(const uint4*)&Kb[kvbase + (size_t)(r0 + 64 + srow) * HD + sc8];
    k1 = *(const uint4*)&Kb[kvbase + (size_t)(r0 + 64 + srow + 32) * HD + sc8];
    v0 = *(const uint4*)&Vtb[kvbase + (size_t)srow * NSEQ + r0 + 64 + sc8];
    v1 = *(const uint4*)&Vtb[kvbase + (size_t)(srow + 32) * NSEQ + r0 + 64 + sc8];

    const f32x4 zero = {0.f, 0.f, 0.f, 0.f};
    f32x4 o_acc[4];
    #pragma unroll
    for (int i = 0; i < 4; ++i) o_acc[i] = zero;
    float l_l = 0.f;

    #pragma unroll 2
    for (int s = 0; s < 8; ++s) {
        __syncthreads();   // the ONE barrier per tile
        const int cur = s & 1;
        const int j0 = r0 + s * 64;

        if (s < 7) {
            *(uint4*)&Ks[g][cur ^ 1][so0] = k0;
            *(uint4*)&Ks[g][cur ^ 1][so1] = k1;
            *(uint4*)&Vt[g][cur ^ 1][so0] = v0;
            *(uint4*)&Vt[g][cur ^ 1][so1] = v1;
        }
        if (s < 6) {
            const int j2 = r0 + (s + 2) * 64;
            k0 = *(const uint4*)&Kb[kvbase + (size_t)(j2 + srow) * HD + sc8];
            k1 = *(const uint4*)&Kb[kvbase + (size_t)(j2 + srow + 32) * HD + sc8];
            v0 = *(const uint4*)&Vtb[kvbase + (size_t)srow * NSEQ + j2 + sc8];
            v1 = *(const uint4*)&Vtb[kvbase + (size_t)(srow + 32) * NSEQ + j2 + sc8];
        }
        uint4 pk4[4];
        #pragma unroll
        for (int jb = 0; jb < 4; ++jb)
            pk4[jb] = *(const uint4*)(prow + j0 + jb * 16);

        // S^T = K Q^T
        f32x4 sacc[4];
        #pragma unroll
        for (int jb = 0; jb < 4; ++jb) {
            sacc[jb] = zero;
            const bf16x8 kb0 = *(const bf16x8*)&Ks[g][cur][(jb * 16 + col) * 72 + quad * 8];
            const bf16x8 kb1 = *(const bf16x8*)&Ks[g][cur][(jb * 16 + col) * 72 + 32 + quad * 8];
            sacc[jb] = __builtin_amdgcn_mfma_f32_16x16x32_bf16(kb0, aq0, sacc[jb], 0, 0, 0);
            sacc[jb] = __builtin_amdgcn_mfma_f32_16x16x32_bf16(kb1, aq1, sacc[jb], 0, 0, 0);
        }

        // combined bias in log2 domain
        float rbeb[4][4];
        #pragma unroll
        for (int jb = 0; jb < 4; ++jb) {
            const uint4 pkv = pk4[jb];
            rbeb[jb][0] = __uint_as_float((unsigned)tabu[pkv.x & 1023u] << 16) + __uint_as_float(pkv.x & 0xFFFF0000u);
            rbeb[jb][1] = __uint_as_float((unsigned)tabu[pkv.y & 1023u] << 16) + __uint_as_float(pkv.y & 0xFFFF0000u);
            rbeb[jb][2] = __uint_as_float((unsigned)tabu[pkv.z & 1023u] << 16) + __uint_as_float(pkv.z & 0xFFFF0000u);
            rbeb[jb][3] = __uint_as_float((unsigned)tabu[pkv.w & 1023u] << 16) + __uint_as_float(pkv.w & 0xFFFF0000u);
        }

        // fixed-m softmax: p = exp2(s + rb + eb), pack pairs to bf16 words
        float psum = 0.f;
        unsigned Wd[4][2];
        #pragma unroll
        for (int jb = 0; jb < 4; ++jb) {
            const float p0 = exp2f(sacc[jb][0] + rbeb[jb][0]);
            const float p1 = exp2f(sacc[jb][1] + rbeb[jb][1]);
            const float p2 = exp2f(sacc[jb][2] + rbeb[jb][2]);
            const float p3 = exp2f(sacc[jb][3] + rbeb[jb][3]);
            psum += (p0 + p1) + (p2 + p3);
            Wd[jb][0] = pk2(p0, p1);
            Wd[jb][1] = pk2(p2, p3);
        }
        l_l += psum;

        // in-register P redistribution (no LDS round-trip):
        // word W[jb][v] at lane quad qs holds j = 16*jb + 4*qs + 2v + {0,1}.
        // PV A-frag needs lane quad q' to hold j = 32h + 8q' + 2u + {0,1}.
        // hop1: permlane32_swap injects jb&1 into lane bit5
        // hop2: permlane16_swap injects old q1 into lane bit4
        bf16x8 ap0, ap1;
        {
            union { unsigned u[4]; bf16x8 b; } A0, A1;
            #pragma unroll
            for (int j1 = 0; j1 < 2; ++j1) {
                #pragma unroll
                for (int v = 0; v < 2; ++v) {
                    auto h1 = __builtin_amdgcn_permlane32_swap(
                        Wd[2 * j1][v], Wd[2 * j1 + 1][v], false, false);
                    auto h2 = __builtin_amdgcn_permlane16_swap(
                        h1[0], h1[1], false, false);
                    if (j1 == 0) { A0.u[0 + v] = h2[0]; A0.u[2 + v] = h2[1]; }
                    else         { A1.u[0 + v] = h2[0]; A1.u[2 + v] = h2[1]; }
                }
            }
            ap0 = A0.b;
            ap1 = A1.b;
        }

        // O += P V
        #pragma unroll
        for (int db = 0; db < 4; ++db) {
            const bf16x8 vv0 = *(const bf16x8*)&Vt[g][cur][(db * 16 + col) * 72 + quad * 8];
            const bf16x8 vv1 = *(const bf16x8*)&Vt[g][cur][(db * 16 + col) * 72 + 32 + quad * 8];
            o_acc[db] = __builtin_amdgcn_mfma_f32_16x16x32_bf16(ap0, vv0, o_acc[db], 0, 0, 0);
            o_acc[db] = __builtin_amdgcn_mfma_f32_16x16x32_bf16(ap1, vv1, o_acc[db], 0, 0, 0);
        }
    }

    // cross-group combine: group 1 dumps partial O (f32) + l into dead
    // staging LDS; group 0 adds, normalizes, stores.
    float l = l_l;
    l += __shfl_xor(l, 16);
    l += __shfl_xor(l, 32);

    __syncthreads();   // all tiles done; K/V staging LDS is dead
    float* Ored = (float*)&Ks[0][0][0];   // 64 rows x 68 f32 = 17408 B
    float* lred = (float*)&Vt[0][0][0];   // 64 f32
    if (g == 1) {
        #pragma unroll
        for (int db = 0; db < 4; ++db)
            #pragma unroll
            for (int r = 0; r < 4; ++r)
                Ored[(wg * 16 + quad * 4 + r) * 68 + db * 16 + col] = o_acc[db][r];
        if (quad == 0) lred[wg * 16 + col] = l;   // l replicated over quads
    }
    __syncthreads();
    if (g == 0) {
        #pragma unroll
        for (int r = 0; r < 4; ++r) {
            const int ri = wg * 16 + quad * 4 + r;
            const float lr = __shfl(l, wg * 16 + quad * 4 + r) + lred[ri];
            const float inv = 1.f / lr;
            const size_t base = ((size_t)(b * NSEQ) + i0 + ri) * DMODEL + h * HD;
            #pragma unroll
            for (int db = 0; db < 4; ++db) {
                const float ov = o_acc[db][r] + Ored[ri * 68 + db * 16 + col];
                Ob[base + db * 16 + col] = f2bf(ov * inv);
            }
        }
    }
}

// ---------------------------------------------------------------------------
// Proj GEMM (bf16 MFMA), unchanged: 64x64 tiles, BK=32, global_load_lds.
// ---------------------------------------------------------------------------
__global__ __launch_bounds__(256) void proj_gemm(
    const ushort_t* __restrict__ A, const ushort_t* __restrict__ B,
    const float* __restrict__ bias, float* __restrict__ out)
{
    __shared__ __align__(16) ushort_t As[64 * 32];
    __shared__ __align__(16) ushort_t Bs[64 * 32];
    const int t = threadIdx.x;
    const int lane = t & 63, w = t >> 6;
    const int wr = w >> 1, wc = w & 1;
    const int col = lane & 15, quad = lane >> 4;
    const int m0 = blockIdx.y * 64, c0 = blockIdx.x * 64;

    const f32x4 zero = {0.f, 0.f, 0.f, 0.f};
    f32x4 acc[2][2];
    #pragma unroll
    for (int i = 0; i < 2; ++i)
        #pragma unroll
        for (int j = 0; j < 2; ++j) acc[i][j] = zero;

    const int srow = w * 16 + (lane >> 2);
    const int scol = (lane & 3) * 8;
    const ushort_t* Ag = A + (size_t)(m0 + srow) * DMODEL + scol;
    const ushort_t* Bg = B + (size_t)(c0 + srow) * DMODEL + scol;
    ushort_t* Asw = &As[w * 16 * 32];
    ushort_t* Bsw = &Bs[w * 16 * 32];

    for (int k0 = 0; k0 < DMODEL; k0 += 32) {
        __syncthreads();
        gl_lds16(Ag + k0, Asw);
        gl_lds16(Bg + k0, Bsw);
        __syncthreads();
        bf16x8 af[2], bf[2];
        #pragma unroll
        for (int im = 0; im < 2; ++im)
            af[im] = *(const bf16x8*)&As[(wr * 32 + im * 16 + col) * 32 + quad * 8];
        #pragma unroll
        for (int jn = 0; jn < 2; ++jn)
            bf[jn] = *(const bf16x8*)&Bs[(wc * 32 + jn * 16 + col) * 32 + quad * 8];
        #pragma unroll
        for (int im = 0; im < 2; ++im)
            #pragma unroll
            for (int jn = 0; jn < 2; ++jn)
                acc[im][jn] = __builtin_amdgcn_mfma_f32_16x16x32_bf16(af[im], bf[jn], acc[im][jn], 0, 0, 0);
    }

    #pragma unroll
    for (int im = 0; im < 2; ++im) {
        #pragma unroll
        for (int jn = 0; jn < 2; ++jn) {
            const int c = c0 + wc * 32 + jn * 16 + col;
            const float bv = bias[c];
            #pragma unroll
            for (int r = 0; r < 4; ++r) {
                const int m = m0 + wr * 32 + im * 16 + quad * 4 + r;
                out[(size_t)m * DMODEL + c] = acc[im][jn][r] + bv;
            }
        }
    }
}

extern "C" void kernel_launch(void* const* d_in, const int* in_sizes, int n_in,
                              void* d_out, int out_size, void* d_ws, size_t ws_size,
                              hipStream_t stream) {
    const float* x       = (const float*)d_in[0];
    const float* coords  = (const float*)d_in[1];
    const float* elev    = (const float*)d_in[2];
    const float* qkv_w   = (const float*)d_in[3];
    const float* qkv_b   = (const float*)d_in[4];
    const float* proj_w  = (const float*)d_in[5];
    const float* proj_b  = (const float*)d_in[6];
    const float* btable  = (const float*)d_in[7];
    const float* alpha   = (const float*)d_in[8];
    float* out = (float*)d_out;

    ushort_t* wsu = (ushort_t*)d_ws;
    ushort_t* xb  = wsu;
    ushort_t* wqb = wsu + 3145728;
    ushort_t* pwb = wsu + 4915200;
    ushort_t* Qb  = wsu + 5505024;
    ushort_t* Kb  = wsu + 8650752;
    ushort_t* Vtb = wsu + 11796480;
    ushort_t* Ob  = wsu + 14942208;
    unsigned* pck = (unsigned*)(wsu + 18087936);   // 4M uint32 = 16 MB

    prep_kernel<<<CVT_BLOCKS + 4096, 256, 0, stream>>>(
        x, qkv_w, proj_w, wsu, coords, elev, alpha, pck);
    qkv_gemm<<<dim3(36, 32), 256, 0, stream>>>(xb, wqb, qkv_b, Qb, Kb, Vtb);
    attn_mfma<<<768, 512, 0, stream>>>(Qb, Kb, Vtb, pck, btable, Ob);
    proj_gemm<<<dim3(12, 64), 256, 0, stream>>>(Ob, pwb, proj_b, out);
}

// Round 5
// 185.936 us; speedup vs baseline: 1.0761x; 1.0761x over previous
//
#include <hip/hip_runtime.h>
#include <hip/hip_bf16.h>
#include <math.h>

#define NH 12
#define HD 64
#define NSEQ 1024
#define DMODEL 768
#define LOG2E 1.44269504f

typedef unsigned short ushort_t;
typedef float f32x4 __attribute__((ext_vector_type(4)));
typedef short bf16x8 __attribute__((ext_vector_type(8)));

__device__ __forceinline__ ushort_t f2bf(float f) {
    unsigned int u = __float_as_uint(f);
    u += 0x7FFFu + ((u >> 16) & 1u);   // RNE
    return (ushort_t)(u >> 16);
}

__device__ __forceinline__ unsigned pk2(float x, float y) {
    __hip_bfloat162 t = __float22bfloat162_rn(make_float2(x, y));
    union { __hip_bfloat162 b; unsigned u; } c; c.b = t;
    return c.u;
}

// async global->LDS DMA, 16B per lane; LDS dest = wave-uniform base + lane*16
__device__ __forceinline__ void gl_lds16(const ushort_t* g, ushort_t* l) {
    __builtin_amdgcn_global_load_lds(
        (const __attribute__((address_space(1))) unsigned int*)g,
        (__attribute__((address_space(3))) unsigned int*)l, 16, 0, 0);
}

// ---------------------------------------------------------------------------
// prep kernel: blocks [0,2688) convert x/qkv_w/proj_w fp32->bf16;
// blocks [2688, 6784) compute packed bias (bf16(elev*log2e)<<16 | bucket).
// ---------------------------------------------------------------------------
#define XB_N   3145728u
#define WQB_N  1769472u
#define PWB_N  589824u
#define CVT_BLOCKS 2688

__device__ __forceinline__ int bucketf(int rel) {
    const int n = -rel;
    const int u = (n < 0) ? 16 : 0;
    const int a = n < 0 ? -n : n;
    if (a < 8) return u + a;
    int v = 8 + (int)(log2f((float)a * 0.125f) * 2.0f + 1e-4f);
    if (v > 15) v = 15;
    return u + v;
}

__global__ __launch_bounds__(256) void prep_kernel(
    const float* __restrict__ x, const float* __restrict__ w1,
    const float* __restrict__ w2, ushort_t* __restrict__ dst,
    const float* __restrict__ coords, const float* __restrict__ elev,
    const float* __restrict__ alpha_p, unsigned* __restrict__ pack)
{
    const int t = threadIdx.x;
    if (blockIdx.x < CVT_BLOCKS) {
        const unsigned i = blockIdx.x * 256 + t;      // 8-elem chunk id
        const unsigned n0 = XB_N / 8, n1 = n0 + WQB_N / 8, n2 = n1 + PWB_N / 8;
        if (i >= n2) return;
        const float* src; unsigned off;
        if (i < n0)      { src = x;  off = i; }
        else if (i < n1) { src = w1; off = i - n0; }
        else             { src = w2; off = i - n1; }
        const float4 a = ((const float4*)src)[off * 2];
        const float4 b = ((const float4*)src)[off * 2 + 1];
        uint4 pk;
        pk.x = pk2(a.x, a.y); pk.y = pk2(a.z, a.w);
        pk.z = pk2(b.x, b.y); pk.w = pk2(b.z, b.w);
        ((uint4*)dst)[i] = pk;
    } else {
        const int blk = blockIdx.x - CVT_BLOCKS;
        const int b = blk >> 10, i = blk & 1023;
        const float alpha = alpha_p[0];
        const float2 ci = *(const float2*)&coords[(size_t)(b * NSEQ + i) * 2];
        const int cxi = (int)(ci.x * 128.0f), cyi = (int)(ci.y * 128.0f);
        const float ei = elev[b * NSEQ + i];
        const int j0 = t * 4;
        const float4 c01 = *(const float4*)&coords[(size_t)(b * NSEQ + j0) * 2];
        const float4 c23 = *(const float4*)&coords[(size_t)(b * NSEQ + j0 + 2) * 2];
        const float4 ej4 = *(const float4*)&elev[b * NSEQ + j0];
        const float cjx[4] = {c01.x, c01.z, c23.x, c23.z};
        const float cjy[4] = {c01.y, c01.w, c23.y, c23.w};
        const float ejv[4] = {ej4.x, ej4.y, ej4.z, ej4.w};
        unsigned r[4];
        #pragma unroll
        for (int k = 0; k < 4; ++k) {
            const int bx = bucketf(cxi - (int)(cjx[k] * 128.0f));
            const int by = bucketf(cyi - (int)(cjy[k] * 128.0f));
            const int idx = (bx << 5) + by;
            const float ed = (ejv[k] - ei) * 1e-3f;
            const float eb = fmaxf(-alpha * fmaxf(ed, 0.0f), -10.0f) * LOG2E;
            r[k] = ((unsigned)f2bf(eb) << 16) | (unsigned)idx;
        }
        uint4 o; o.x = r[0]; o.y = r[1]; o.z = r[2]; o.w = r[3];
        *(uint4*)&pack[((size_t)b << 20) + (size_t)i * NSEQ + j0] = o;
    }
}

// ---------------------------------------------------------------------------
// QKV GEMM (bf16 MFMA), 128M x 64N tiles -> grid 36x32 = 1152 blocks
// (4.5 blocks/CU). m97-style global_load_lds staging, LDS 12 KB.
// Whole block maps to exactly one of Q/K/V (64-col tile within one (s,h)).
// Q pre-scaled by 0.125*log2e; V transposed [bh][d][n].
// ---------------------------------------------------------------------------
__global__ __launch_bounds__(256) void qkv_gemm(
    const ushort_t* __restrict__ A, const ushort_t* __restrict__ B,
    const float* __restrict__ bias,
    ushort_t* __restrict__ Qb, ushort_t* __restrict__ Kb, ushort_t* __restrict__ Vtb)
{
    __shared__ __align__(16) ushort_t SM[6144];   // As [128*32], Bs [64*32]
    ushort_t* Asb = SM;
    ushort_t* Bsb = SM + 4096;
    const int t = threadIdx.x;
    const int lane = t & 63, w = t >> 6;
    const int wr = w >> 1, wc = w & 1;            // wave: 64 M-rows x 32 N-cols
    const int col = lane & 15, quad = lane >> 4;
    const int m0 = blockIdx.y * 128, c0 = blockIdx.x * 64;

    const f32x4 zero = {0.f, 0.f, 0.f, 0.f};
    f32x4 acc[4][2];
    #pragma unroll
    for (int i = 0; i < 4; ++i)
        #pragma unroll
        for (int j = 0; j < 2; ++j) acc[i][j] = zero;

    // staging: wave w stages A rows 32w..32w+31 (2 DMA) and B rows 16w..16w+15 (1 DMA)
    const int arow = w * 32 + (lane >> 2);
    const int brow = w * 16 + (lane >> 2);
    const int scol = (lane & 3) * 8;
    const ushort_t* Ag = A + (size_t)(m0 + arow) * DMODEL + scol;
    const ushort_t* Bg = B + (size_t)(c0 + brow) * DMODEL + scol;
    ushort_t* Asw = Asb + w * 32 * 32;
    ushort_t* Bsw = Bsb + w * 16 * 32;

    for (int k0 = 0; k0 < DMODEL; k0 += 32) {
        __syncthreads();
        gl_lds16(Ag + k0, Asw);
        gl_lds16(Ag + (size_t)16 * DMODEL + k0, Asw + 16 * 32);
        gl_lds16(Bg + k0, Bsw);
        __syncthreads();   // compiler drains vmcnt here
        bf16x8 af[4], bf[2];
        #pragma unroll
        for (int im = 0; im < 4; ++im)
            af[im] = *(const bf16x8*)&Asb[(wr * 64 + im * 16 + col) * 32 + quad * 8];
        #pragma unroll
        for (int jn = 0; jn < 2; ++jn)
            bf[jn] = *(const bf16x8*)&Bsb[(wc * 32 + jn * 16 + col) * 32 + quad * 8];
        #pragma unroll
        for (int im = 0; im < 4; ++im)
            #pragma unroll
            for (int jn = 0; jn < 2; ++jn)
                acc[im][jn] = __builtin_amdgcn_mfma_f32_16x16x32_bf16(af[im], bf[jn], acc[im][jn], 0, 0, 0);
    }

    const int s = c0 / DMODEL;                    // block-uniform
    const int h = (c0 % DMODEL) >> 6;
    const int b = m0 >> 10;
    const int bh = b * NH + h;
    const int n0 = (m0 & (NSEQ - 1)) + wr * 64;
    const int d0 = (c0 & 63);                     // 0 (tiles are h-aligned)
    const int cb = c0 + wc * 32;

    __syncthreads();   // retire all MFMA fragment reads before LDS reuse

    if (s < 2) {
        // LDS transpose epilogue: per im-block the wave writes a 16x32 bf16
        // tile (stride 40), reads rows back, stores one coalesced uint4/lane.
        ushort_t* lt = SM + w * 1280;             // 16 rows x 40
        ushort_t* dst = (s == 0) ? Qb : Kb;
        const float sc = (s == 0) ? 0.125f * LOG2E : 1.0f;
        float bv[2];
        #pragma unroll
        for (int jn = 0; jn < 2; ++jn) bv[jn] = bias[cb + jn * 16 + col];
        const int row16 = lane >> 2, seg = lane & 3;
        #pragma unroll
        for (int im = 0; im < 4; ++im) {
            #pragma unroll
            for (int jn = 0; jn < 2; ++jn) {
                const f32x4 a = acc[im][jn];
                #pragma unroll
                for (int r = 0; r < 4; ++r)
                    lt[(quad * 4 + r) * 40 + jn * 16 + col] = f2bf((a[r] + bv[jn]) * sc);
            }
            // same-wave DS is in-order: reads below see the writes above
            const uint4 u0 = *(const uint4*)&lt[row16 * 40 + seg * 8];
            const size_t gb = ((size_t)bh * NSEQ + n0 + im * 16 + row16) * HD
                            + wc * 32 + seg * 8;
            *(uint4*)&dst[gb] = u0;
        }
    } else {
        #pragma unroll
        for (int im = 0; im < 4; ++im) {
            #pragma unroll
            for (int jn = 0; jn < 2; ++jn) {
                const int d = wc * 32 + jn * 16 + col;
                const float bvv = bias[cb + jn * 16 + col];
                const f32x4 a = acc[im][jn];
                uint2 p;
                p.x = pk2(a[0] + bvv, a[1] + bvv);
                p.y = pk2(a[2] + bvv, a[3] + bvv);
                *(uint2*)&Vtb[((size_t)bh * HD + d) * NSEQ + n0 + im * 16 + quad * 4] = p;
            }
        }
    }
    (void)d0;
}

// ---------------------------------------------------------------------------
// Fused flash attention, R4: back to the R0 structure (256 thr, Ps via LDS,
// measured 52.4 us) plus three latency cuts:
//  (1) bias prefetch pipeline: pk4 global loads 2 tiles deep (pk4l), tabu
//      gathers 1 tile deep (rbn computed under the PV MFMA window) -> the
//      random ds_read_u16 gathers leave the S->exp2 critical chain.
//  (2) s_setprio(1) around QK and PV MFMA clusters.
//  (3) bijective XCD swizzle (768 = 8*96): all 16 q-tiles of one (b,h) on
//      one XCD -> K/V/pack L2-resident.
// ---------------------------------------------------------------------------
#define RBIAS(u) (__uint_as_float((unsigned)tabu[(u) & 1023u] << 16) \
                + __uint_as_float((u) & 0xFFFF0000u))

__global__ __launch_bounds__(256) void attn_mfma(
    const ushort_t* __restrict__ Qb, const ushort_t* __restrict__ Kb,
    const ushort_t* __restrict__ Vtb,
    const unsigned* __restrict__ pack,
    const float* __restrict__ table,
    ushort_t* __restrict__ Ob)
{
    __shared__ __align__(16) ushort_t Ks[2][64 * 72];
    __shared__ __align__(16) ushort_t Vt[2][64 * 72];
    __shared__ __align__(16) ushort_t Ps[64 * 72];
    __shared__ ushort_t tabu[1024];   // bf16(table[:,h] * log2e)

    const int t = threadIdx.x;
    const int lane = t & 63, w = t >> 6;
    const int col = lane & 15, quad = lane >> 4;
    const int bid = (blockIdx.x & 7) * 96 + (blockIdx.x >> 3);   // XCD swizzle
    const int it = bid & 15, bh = bid >> 4;
    const int h = bh % NH, b = bh / NH;
    const int i0 = it * 64;

    for (int i = t; i < 1024; i += 256)
        tabu[i] = f2bf(table[i * NH + h] * LOG2E);

    const ushort_t* Qg = Qb + ((size_t)bh * NSEQ + i0 + w * 16 + col) * HD;
    const bf16x8 aq0 = *(const bf16x8*)(Qg + quad * 8);
    const bf16x8 aq1 = *(const bf16x8*)(Qg + 32 + quad * 8);

    const size_t kvbase = (size_t)bh * NSEQ * HD;
    const unsigned* prow = pack + ((size_t)b << 20)
                         + (size_t)(i0 + w * 16 + col) * NSEQ + quad * 4;

    const int srow = t >> 3, sc8 = (t & 7) * 8;
    const int so0 = srow * 72 + sc8;
    const int so1 = (srow + 32) * 72 + sc8;

    uint4 k0 = *(const uint4*)&Kb[kvbase + (size_t)srow * HD + sc8];
    uint4 k1 = *(const uint4*)&Kb[kvbase + (size_t)(srow + 32) * HD + sc8];
    uint4 v0 = *(const uint4*)&Vtb[kvbase + (size_t)srow * NSEQ + sc8];
    uint4 v1 = *(const uint4*)&Vtb[kvbase + (size_t)(srow + 32) * NSEQ + sc8];
    *(uint4*)&Ks[0][so0] = k0;
    *(uint4*)&Ks[0][so1] = k1;
    *(uint4*)&Vt[0][so0] = v0;
    *(uint4*)&Vt[0][so1] = v1;
    k0 = *(const uint4*)&Kb[kvbase + (size_t)(64 + srow) * HD + sc8];
    k1 = *(const uint4*)&Kb[kvbase + (size_t)(64 + srow + 32) * HD + sc8];
    v0 = *(const uint4*)&Vtb[kvbase + (size_t)srow * NSEQ + 64 + sc8];
    v1 = *(const uint4*)&Vtb[kvbase + (size_t)(srow + 32) * NSEQ + 64 + sc8];

    // bias pipeline: pk4g = pack words for the tile to gather next;
    // pk4l = loads in flight two tiles ahead; rbc = bias for current tile.
    uint4 pk4g[4], pk4l[4];
    #pragma unroll
    for (int jb = 0; jb < 4; ++jb)
        pk4g[jb] = *(const uint4*)(prow + jb * 16);

    __syncthreads();   // tabu (and buf0 staging) visible

    float rbc[4][4], rbn[4][4];
    #pragma unroll
    for (int jb = 0; jb < 4; ++jb) {
        const uint4 pkv = pk4g[jb];
        rbc[jb][0] = RBIAS(pkv.x);
        rbc[jb][1] = RBIAS(pkv.y);
        rbc[jb][2] = RBIAS(pkv.z);
        rbc[jb][3] = RBIAS(pkv.w);
    }
    #pragma unroll
    for (int jb = 0; jb < 4; ++jb)
        pk4g[jb] = *(const uint4*)(prow + 64 + jb * 16);

    const f32x4 zero = {0.f, 0.f, 0.f, 0.f};
    f32x4 o_acc[4];
    #pragma unroll
    for (int i = 0; i < 4; ++i) o_acc[i] = zero;
    float l_l = 0.f;

    #pragma unroll 2
    for (int jt = 0; jt < 16; ++jt) {
        __syncthreads();   // the ONE barrier per tile
        const int cur = jt & 1;

        if (jt < 15) {
            *(uint4*)&Ks[cur ^ 1][so0] = k0;
            *(uint4*)&Ks[cur ^ 1][so1] = k1;
            *(uint4*)&Vt[cur ^ 1][so0] = v0;
            *(uint4*)&Vt[cur ^ 1][so1] = v1;
        }
        if (jt < 14) {
            const int j2 = (jt + 2) * 64;
            k0 = *(const uint4*)&Kb[kvbase + (size_t)(j2 + srow) * HD + sc8];
            k1 = *(const uint4*)&Kb[kvbase + (size_t)(j2 + srow + 32) * HD + sc8];
            v0 = *(const uint4*)&Vtb[kvbase + (size_t)srow * NSEQ + j2 + sc8];
            v1 = *(const uint4*)&Vtb[kvbase + (size_t)(srow + 32) * NSEQ + j2 + sc8];
            #pragma unroll
            for (int jb = 0; jb < 4; ++jb)
                pk4l[jb] = *(const uint4*)(prow + j2 + jb * 16);
        }

        // S^T = K Q^T
        f32x4 sacc[4];
        __builtin_amdgcn_s_setprio(1);
        #pragma unroll
        for (int jb = 0; jb < 4; ++jb) {
            sacc[jb] = zero;
            const bf16x8 kb0 = *(const bf16x8*)&Ks[cur][(jb * 16 + col) * 72 + quad * 8];
            const bf16x8 kb1 = *(const bf16x8*)&Ks[cur][(jb * 16 + col) * 72 + 32 + quad * 8];
            sacc[jb] = __builtin_amdgcn_mfma_f32_16x16x32_bf16(kb0, aq0, sacc[jb], 0, 0, 0);
            sacc[jb] = __builtin_amdgcn_mfma_f32_16x16x32_bf16(kb1, aq1, sacc[jb], 0, 0, 0);
        }
        __builtin_amdgcn_s_setprio(0);

        // fixed-m softmax with PREFETCHED bias: p = exp2(s + rbc)
        float psum = 0.f;
        #pragma unroll
        for (int jb = 0; jb < 4; ++jb) {
            const float p0 = exp2f(sacc[jb][0] + rbc[jb][0]);
            const float p1 = exp2f(sacc[jb][1] + rbc[jb][1]);
            const float p2 = exp2f(sacc[jb][2] + rbc[jb][2]);
            const float p3 = exp2f(sacc[jb][3] + rbc[jb][3]);
            psum += (p0 + p1) + (p2 + p3);
            uint2 st;
            st.x = pk2(p0, p1);
            st.y = pk2(p2, p3);
            *(uint2*)&Ps[(w * 16 + col) * 72 + jb * 16 + quad * 4] = st;
        }
        l_l += psum;

        // O += P V  (wave-private P rows; same-wave DS in-order, no barrier)
        // next-tile bias gathers are interleaved with the PV MFMAs so the
        // random tabu ds_reads complete under the matrix pipe.
        const bf16x8 ap0 = *(const bf16x8*)&Ps[(w * 16 + col) * 72 + quad * 8];
        const bf16x8 ap1 = *(const bf16x8*)&Ps[(w * 16 + col) * 72 + 32 + quad * 8];
        __builtin_amdgcn_s_setprio(1);
        #pragma unroll
        for (int db = 0; db < 4; ++db) {
            const bf16x8 vv0 = *(const bf16x8*)&Vt[cur][(db * 16 + col) * 72 + quad * 8];
            const bf16x8 vv1 = *(const bf16x8*)&Vt[cur][(db * 16 + col) * 72 + 32 + quad * 8];
            o_acc[db] = __builtin_amdgcn_mfma_f32_16x16x32_bf16(ap0, vv0, o_acc[db], 0, 0, 0);
            o_acc[db] = __builtin_amdgcn_mfma_f32_16x16x32_bf16(ap1, vv1, o_acc[db], 0, 0, 0);
            if (jt < 15) {
                const uint4 pkv = pk4g[db];
                rbn[db][0] = RBIAS(pkv.x);
                rbn[db][1] = RBIAS(pkv.y);
                rbn[db][2] = RBIAS(pkv.z);
                rbn[db][3] = RBIAS(pkv.w);
            }
        }
        __builtin_amdgcn_s_setprio(0);

        // rotate pipeline regs (renamed away by the unroll)
        #pragma unroll
        for (int jb = 0; jb < 4; ++jb) {
            pk4g[jb] = pk4l[jb];
            rbc[jb][0] = rbn[jb][0];
            rbc[jb][1] = rbn[jb][1];
            rbc[jb][2] = rbn[jb][2];
            rbc[jb][3] = rbn[jb][3];
        }
    }

    // epilogue: reduce l over quads, normalize, store bf16
    float l = l_l;
    l += __shfl_xor(l, 16);
    l += __shfl_xor(l, 32);
    #pragma unroll
    for (int r = 0; r < 4; ++r) {
        const float lr = __shfl(l, w * 16 + quad * 4 + r);
        const float inv = 1.f / lr;
        const int ri = w * 16 + quad * 4 + r;
        const size_t base = ((size_t)(b * NSEQ) + i0 + ri) * DMODEL + h * HD;
        #pragma unroll
        for (int db = 0; db < 4; ++db)
            Ob[base + db * 16 + col] = f2bf(o_acc[db][r] * inv);
    }
}

// ---------------------------------------------------------------------------
// Proj GEMM (bf16 MFMA), unchanged: 64x64 tiles, BK=32, global_load_lds.
// ---------------------------------------------------------------------------
__global__ __launch_bounds__(256) void proj_gemm(
    const ushort_t* __restrict__ A, const ushort_t* __restrict__ B,
    const float* __restrict__ bias, float* __restrict__ out)
{
    __shared__ __align__(16) ushort_t As[64 * 32];
    __shared__ __align__(16) ushort_t Bs[64 * 32];
    const int t = threadIdx.x;
    const int lane = t & 63, w = t >> 6;
    const int wr = w >> 1, wc = w & 1;
    const int col = lane & 15, quad = lane >> 4;
    const int m0 = blockIdx.y * 64, c0 = blockIdx.x * 64;

    const f32x4 zero = {0.f, 0.f, 0.f, 0.f};
    f32x4 acc[2][2];
    #pragma unroll
    for (int i = 0; i < 2; ++i)
        #pragma unroll
        for (int j = 0; j < 2; ++j) acc[i][j] = zero;

    const int srow = w * 16 + (lane >> 2);
    const int scol = (lane & 3) * 8;
    const ushort_t* Ag = A + (size_t)(m0 + srow) * DMODEL + scol;
    const ushort_t* Bg = B + (size_t)(c0 + srow) * DMODEL + scol;
    ushort_t* Asw = &As[w * 16 * 32];
    ushort_t* Bsw = &Bs[w * 16 * 32];

    for (int k0 = 0; k0 < DMODEL; k0 += 32) {
        __syncthreads();
        gl_lds16(Ag + k0, Asw);
        gl_lds16(Bg + k0, Bsw);
        __syncthreads();
        bf16x8 af[2], bf[2];
        #pragma unroll
        for (int im = 0; im < 2; ++im)
            af[im] = *(const bf16x8*)&As[(wr * 32 + im * 16 + col) * 32 + quad * 8];
        #pragma unroll
        for (int jn = 0; jn < 2; ++jn)
            bf[jn] = *(const bf16x8*)&Bs[(wc * 32 + jn * 16 + col) * 32 + quad * 8];
        #pragma unroll
        for (int im = 0; im < 2; ++im)
            #pragma unroll
            for (int jn = 0; jn < 2; ++jn)
                acc[im][jn] = __builtin_amdgcn_mfma_f32_16x16x32_bf16(af[im], bf[jn], acc[im][jn], 0, 0, 0);
    }

    #pragma unroll
    for (int im = 0; im < 2; ++im) {
        #pragma unroll
        for (int jn = 0; jn < 2; ++jn) {
            const int c = c0 + wc * 32 + jn * 16 + col;
            const float bv = bias[c];
            #pragma unroll
            for (int r = 0; r < 4; ++r) {
                const int m = m0 + wr * 32 + im * 16 + quad * 4 + r;
                out[(size_t)m * DMODEL + c] = acc[im][jn][r] + bv;
            }
        }
    }
}

extern "C" void kernel_launch(void* const* d_in, const int* in_sizes, int n_in,
                              void* d_out, int out_size, void* d_ws, size_t ws_size,
                              hipStream_t stream) {
    const float* x       = (const float*)d_in[0];
    const float* coords  = (const float*)d_in[1];
    const float* elev    = (const float*)d_in[2];
    const float* qkv_w   = (const float*)d_in[3];
    const float* qkv_b   = (const float*)d_in[4];
    const float* proj_w  = (const float*)d_in[5];
    const float* proj_b  = (const float*)d_in[6];
    const float* btable  = (const float*)d_in[7];
    const float* alpha   = (const float*)d_in[8];
    float* out = (float*)d_out;

    ushort_t* wsu = (ushort_t*)d_ws;
    ushort_t* xb  = wsu;
    ushort_t* wqb = wsu + 3145728;
    ushort_t* pwb = wsu + 4915200;
    ushort_t* Qb  = wsu + 5505024;
    ushort_t* Kb  = wsu + 8650752;
    ushort_t* Vtb = wsu + 11796480;
    ushort_t* Ob  = wsu + 14942208;
    unsigned* pck = (unsigned*)(wsu + 18087936);   // 4M uint32 = 16 MB

    prep_kernel<<<CVT_BLOCKS + 4096, 256, 0, stream>>>(
        x, qkv_w, proj_w, wsu, coords, elev, alpha, pck);
    qkv_gemm<<<dim3(36, 32), 256, 0, stream>>>(xb, wqb, qkv_b, Qb, Kb, Vtb);
    attn_mfma<<<768, 256, 0, stream>>>(Qb, Kb, Vtb, pck, btable, Ob);
    proj_gemm<<<dim3(12, 64), 256, 0, stream>>>(Ob, pwb, proj_b, out);
}

// Round 6
// 182.694 us; speedup vs baseline: 1.0952x; 1.0177x over previous
//
#include <hip/hip_runtime.h>
#include <hip/hip_bf16.h>
#include <math.h>

#define NH 12
#define HD 64
#define NSEQ 1024
#define DMODEL 768
#define LOG2E 1.44269504f

typedef unsigned short ushort_t;
typedef float f32x4 __attribute__((ext_vector_type(4)));
typedef short bf16x8 __attribute__((ext_vector_type(8)));

__device__ __forceinline__ ushort_t f2bf(float f) {
    unsigned int u = __float_as_uint(f);
    u += 0x7FFFu + ((u >> 16) & 1u);   // RNE
    return (ushort_t)(u >> 16);
}

__device__ __forceinline__ unsigned pk2(float x, float y) {
    __hip_bfloat162 t = __float22bfloat162_rn(make_float2(x, y));
    union { __hip_bfloat162 b; unsigned u; } c; c.b = t;
    return c.u;
}

// async global->LDS DMA, 16B per lane; LDS dest = wave-uniform base + lane*16
__device__ __forceinline__ void gl_lds16(const ushort_t* g, ushort_t* l) {
    __builtin_amdgcn_global_load_lds(
        (const __attribute__((address_space(1))) unsigned int*)g,
        (__attribute__((address_space(3))) unsigned int*)l, 16, 0, 0);
}

// ---------------------------------------------------------------------------
// prep kernel (cvt only now): convert x/qkv_w/proj_w fp32->bf16.
// The bias-pack half moved into the qkv_gemm launch (independent work that
// fills the GEMM's tail bubbles and saves a launch gap).
// ---------------------------------------------------------------------------
#define XB_N   3145728u
#define WQB_N  1769472u
#define PWB_N  589824u
#define CVT_BLOCKS 2688

__global__ __launch_bounds__(256) void prep_kernel(
    const float* __restrict__ x, const float* __restrict__ w1,
    const float* __restrict__ w2, ushort_t* __restrict__ dst)
{
    const int t = threadIdx.x;
    const unsigned i = blockIdx.x * 256 + t;      // 8-elem chunk id
    const unsigned n0 = XB_N / 8, n1 = n0 + WQB_N / 8, n2 = n1 + PWB_N / 8;
    if (i >= n2) return;
    const float* src; unsigned off;
    if (i < n0)      { src = x;  off = i; }
    else if (i < n1) { src = w1; off = i - n0; }
    else             { src = w2; off = i - n1; }
    const float4 a = ((const float4*)src)[off * 2];
    const float4 b = ((const float4*)src)[off * 2 + 1];
    uint4 pk;
    pk.x = pk2(a.x, a.y); pk.y = pk2(a.z, a.w);
    pk.z = pk2(b.x, b.y); pk.w = pk2(b.z, b.w);
    ((uint4*)dst)[i] = pk;
}

__device__ __forceinline__ int bucketf(int rel) {
    const int n = -rel;
    const int u = (n < 0) ? 16 : 0;
    const int a = n < 0 ? -n : n;
    if (a < 8) return u + a;
    int v = 8 + (int)(log2f((float)a * 0.125f) * 2.0f + 1e-4f);
    if (v > 15) v = 15;
    return u + v;
}

// ---------------------------------------------------------------------------
// QKV GEMM, R5: m97-style 128x128 tiles (was 128x64). 4 waves, each owns a
// 64x64 quadrant (acc[4][4]); 16 MFMA per 8 ds_read_b128 per BK=32 step.
// Grid: blocks [0,576) GEMM (XCD-swizzled so each XCD owns whole M-panels);
// blocks [576, 4672) compute the packed attention bias
// (bf16(elev*log2e)<<16 | bucket) — independent work, dispatched after.
// Each wave's 64 cols = exactly one head; Q pre-scaled by 0.125*log2e;
// V transposed [bh][d][n].
// ---------------------------------------------------------------------------
#define QKV_BLOCKS 576

__global__ __launch_bounds__(256) void qkv_gemm(
    const ushort_t* __restrict__ A, const ushort_t* __restrict__ B,
    const float* __restrict__ bias,
    ushort_t* __restrict__ Qb, ushort_t* __restrict__ Kb, ushort_t* __restrict__ Vtb,
    const float* __restrict__ coords, const float* __restrict__ elev,
    const float* __restrict__ alpha_p, unsigned* __restrict__ pack)
{
    __shared__ __align__(16) ushort_t SM[9216];   // As 128x32, Bs 128x32 (+lt reuse)
    const int t = threadIdx.x;

    if (blockIdx.x >= QKV_BLOCKS) {
        // ---- bias-pack half (formerly prep's second phase) ----
        const int blk = blockIdx.x - QKV_BLOCKS;
        const int b = blk >> 10, i = blk & 1023;
        const float alpha = alpha_p[0];
        const float2 ci = *(const float2*)&coords[(size_t)(b * NSEQ + i) * 2];
        const int cxi = (int)(ci.x * 128.0f), cyi = (int)(ci.y * 128.0f);
        const float ei = elev[b * NSEQ + i];
        const int j0 = t * 4;
        const float4 c01 = *(const float4*)&coords[(size_t)(b * NSEQ + j0) * 2];
        const float4 c23 = *(const float4*)&coords[(size_t)(b * NSEQ + j0 + 2) * 2];
        const float4 ej4 = *(const float4*)&elev[b * NSEQ + j0];
        const float cjx[4] = {c01.x, c01.z, c23.x, c23.z};
        const float cjy[4] = {c01.y, c01.w, c23.y, c23.w};
        const float ejv[4] = {ej4.x, ej4.y, ej4.z, ej4.w};
        unsigned r[4];
        #pragma unroll
        for (int k = 0; k < 4; ++k) {
            const int bx = bucketf(cxi - (int)(cjx[k] * 128.0f));
            const int by = bucketf(cyi - (int)(cjy[k] * 128.0f));
            const int idx = (bx << 5) + by;
            const float ed = (ejv[k] - ei) * 1e-3f;
            const float eb = fmaxf(-alpha * fmaxf(ed, 0.0f), -10.0f) * LOG2E;
            r[k] = ((unsigned)f2bf(eb) << 16) | (unsigned)idx;
        }
        uint4 o; o.x = r[0]; o.y = r[1]; o.z = r[2]; o.w = r[3];
        *(uint4*)&pack[((size_t)b << 20) + (size_t)i * NSEQ + j0] = o;
        return;
    }

    // ---- GEMM half ----
    // XCD swizzle: 576 = 8 XCDs x 72; consecutive lid share the same M-panel
    // (runs of 18), so each XCD owns 4 complete M-panels -> A rows L2-local.
    const int lid = (blockIdx.x & 7) * 72 + (blockIdx.x >> 3);
    const int bx = lid % 18, by = lid / 18;
    const int m0 = by * 128, c0 = bx * 128;

    ushort_t* Asb = SM;
    ushort_t* Bsb = SM + 4096;
    const int lane = t & 63, w = t >> 6;
    const int wr = w >> 1, wc = w & 1;            // wave quadrant: 64M x 64N
    const int col = lane & 15, quad = lane >> 4;

    const f32x4 zero = {0.f, 0.f, 0.f, 0.f};
    f32x4 acc[4][4];
    #pragma unroll
    for (int i = 0; i < 4; ++i)
        #pragma unroll
        for (int j = 0; j < 4; ++j) acc[i][j] = zero;

    // staging: wave w stages A rows 32w..32w+31 and B rows 32w..32w+31 (2 DMA each)
    const int arow = w * 32 + (lane >> 2);
    const int scol = (lane & 3) * 8;
    const ushort_t* Ag = A + (size_t)(m0 + arow) * DMODEL + scol;
    const ushort_t* Bg = B + (size_t)(c0 + arow) * DMODEL + scol;
    ushort_t* Asw = Asb + w * 32 * 32;
    ushort_t* Bsw = Bsb + w * 32 * 32;

    for (int k0 = 0; k0 < DMODEL; k0 += 32) {
        __syncthreads();
        gl_lds16(Ag + k0, Asw);
        gl_lds16(Ag + (size_t)16 * DMODEL + k0, Asw + 16 * 32);
        gl_lds16(Bg + k0, Bsw);
        gl_lds16(Bg + (size_t)16 * DMODEL + k0, Bsw + 16 * 32);
        __syncthreads();   // compiler drains vmcnt here
        bf16x8 af[4], bf[4];
        #pragma unroll
        for (int im = 0; im < 4; ++im)
            af[im] = *(const bf16x8*)&Asb[(wr * 64 + im * 16 + col) * 32 + quad * 8];
        #pragma unroll
        for (int jn = 0; jn < 4; ++jn)
            bf[jn] = *(const bf16x8*)&Bsb[(wc * 64 + jn * 16 + col) * 32 + quad * 8];
        #pragma unroll
        for (int im = 0; im < 4; ++im)
            #pragma unroll
            for (int jn = 0; jn < 4; ++jn)
                acc[im][jn] = __builtin_amdgcn_mfma_f32_16x16x32_bf16(af[im], bf[jn], acc[im][jn], 0, 0, 0);
    }

    const int cbw = c0 + wc * 64;                 // wave's 64-col base = one head
    const int s = cbw / DMODEL;                   // wave-uniform
    const int h = (cbw % DMODEL) >> 6;
    const int b = m0 >> 10;
    const int bh = b * NH + h;
    const int n0 = (m0 & (NSEQ - 1)) + wr * 64;

    float bv[4];
    #pragma unroll
    for (int jn = 0; jn < 4; ++jn) bv[jn] = bias[cbw + jn * 16 + col];

    __syncthreads();   // retire all MFMA fragment reads before LDS reuse

    if (s < 2) {
        // LDS transpose epilogue: per im-block the wave writes a 16x64 bf16
        // tile (stride 72), reads rows back, stores 2 coalesced uint4/lane.
        ushort_t* lt = SM + w * 1152;             // 16 rows x 72
        ushort_t* dst = (s == 0) ? Qb : Kb;
        const float sc = (s == 0) ? 0.125f * LOG2E : 1.0f;
        const int row16 = lane >> 2, seg = lane & 3;
        #pragma unroll
        for (int im = 0; im < 4; ++im) {
            #pragma unroll
            for (int jn = 0; jn < 4; ++jn) {
                const f32x4 a = acc[im][jn];
                #pragma unroll
                for (int r = 0; r < 4; ++r)
                    lt[(quad * 4 + r) * 72 + jn * 16 + col] = f2bf((a[r] + bv[jn]) * sc);
            }
            // same-wave DS is in-order: reads below see the writes above
            const uint4 u0 = *(const uint4*)&lt[row16 * 72 + seg * 8];
            const uint4 u1 = *(const uint4*)&lt[row16 * 72 + 32 + seg * 8];
            const size_t gb = ((size_t)bh * NSEQ + n0 + im * 16 + row16) * HD
                            + seg * 8;
            *(uint4*)&dst[gb] = u0;
            *(uint4*)&dst[gb + 32] = u1;
        }
    } else {
        #pragma unroll
        for (int im = 0; im < 4; ++im) {
            #pragma unroll
            for (int jn = 0; jn < 4; ++jn) {
                const int d = jn * 16 + col;
                const float bvv = bv[jn];
                const f32x4 a = acc[im][jn];
                uint2 p;
                p.x = pk2(a[0] + bvv, a[1] + bvv);
                p.y = pk2(a[2] + bvv, a[3] + bvv);
                *(uint2*)&Vtb[((size_t)bh * HD + d) * NSEQ + n0 + im * 16 + quad * 4] = p;
            }
        }
    }
}

// ---------------------------------------------------------------------------
// Fused flash attention (R4 best, unchanged): 256 thr, Ps via LDS, bias
// prefetch pipeline, setprio around MFMA clusters, bijective XCD swizzle.
// ---------------------------------------------------------------------------
#define RBIAS(u) (__uint_as_float((unsigned)tabu[(u) & 1023u] << 16) \
                + __uint_as_float((u) & 0xFFFF0000u))

__global__ __launch_bounds__(256) void attn_mfma(
    const ushort_t* __restrict__ Qb, const ushort_t* __restrict__ Kb,
    const ushort_t* __restrict__ Vtb,
    const unsigned* __restrict__ pack,
    const float* __restrict__ table,
    ushort_t* __restrict__ Ob)
{
    __shared__ __align__(16) ushort_t Ks[2][64 * 72];
    __shared__ __align__(16) ushort_t Vt[2][64 * 72];
    __shared__ __align__(16) ushort_t Ps[64 * 72];
    __shared__ ushort_t tabu[1024];   // bf16(table[:,h] * log2e)

    const int t = threadIdx.x;
    const int lane = t & 63, w = t >> 6;
    const int col = lane & 15, quad = lane >> 4;
    const int bid = (blockIdx.x & 7) * 96 + (blockIdx.x >> 3);   // XCD swizzle
    const int it = bid & 15, bh = bid >> 4;
    const int h = bh % NH, b = bh / NH;
    const int i0 = it * 64;

    for (int i = t; i < 1024; i += 256)
        tabu[i] = f2bf(table[i * NH + h] * LOG2E);

    const ushort_t* Qg = Qb + ((size_t)bh * NSEQ + i0 + w * 16 + col) * HD;
    const bf16x8 aq0 = *(const bf16x8*)(Qg + quad * 8);
    const bf16x8 aq1 = *(const bf16x8*)(Qg + 32 + quad * 8);

    const size_t kvbase = (size_t)bh * NSEQ * HD;
    const unsigned* prow = pack + ((size_t)b << 20)
                         + (size_t)(i0 + w * 16 + col) * NSEQ + quad * 4;

    const int srow = t >> 3, sc8 = (t & 7) * 8;
    const int so0 = srow * 72 + sc8;
    const int so1 = (srow + 32) * 72 + sc8;

    uint4 k0 = *(const uint4*)&Kb[kvbase + (size_t)srow * HD + sc8];
    uint4 k1 = *(const uint4*)&Kb[kvbase + (size_t)(srow + 32) * HD + sc8];
    uint4 v0 = *(const uint4*)&Vtb[kvbase + (size_t)srow * NSEQ + sc8];
    uint4 v1 = *(const uint4*)&Vtb[kvbase + (size_t)(srow + 32) * NSEQ + sc8];
    *(uint4*)&Ks[0][so0] = k0;
    *(uint4*)&Ks[0][so1] = k1;
    *(uint4*)&Vt[0][so0] = v0;
    *(uint4*)&Vt[0][so1] = v1;
    k0 = *(const uint4*)&Kb[kvbase + (size_t)(64 + srow) * HD + sc8];
    k1 = *(const uint4*)&Kb[kvbase + (size_t)(64 + srow + 32) * HD + sc8];
    v0 = *(const uint4*)&Vtb[kvbase + (size_t)srow * NSEQ + 64 + sc8];
    v1 = *(const uint4*)&Vtb[kvbase + (size_t)(srow + 32) * NSEQ + 64 + sc8];

    // bias pipeline: pk4g = pack words for the tile to gather next;
    // pk4l = loads in flight two tiles ahead; rbc = bias for current tile.
    uint4 pk4g[4], pk4l[4];
    #pragma unroll
    for (int jb = 0; jb < 4; ++jb)
        pk4g[jb] = *(const uint4*)(prow + jb * 16);

    __syncthreads();   // tabu (and buf0 staging) visible

    float rbc[4][4], rbn[4][4];
    #pragma unroll
    for (int jb = 0; jb < 4; ++jb) {
        const uint4 pkv = pk4g[jb];
        rbc[jb][0] = RBIAS(pkv.x);
        rbc[jb][1] = RBIAS(pkv.y);
        rbc[jb][2] = RBIAS(pkv.z);
        rbc[jb][3] = RBIAS(pkv.w);
    }
    #pragma unroll
    for (int jb = 0; jb < 4; ++jb)
        pk4g[jb] = *(const uint4*)(prow + 64 + jb * 16);

    const f32x4 zero = {0.f, 0.f, 0.f, 0.f};
    f32x4 o_acc[4];
    #pragma unroll
    for (int i = 0; i < 4; ++i) o_acc[i] = zero;
    float l_l = 0.f;

    #pragma unroll 2
    for (int jt = 0; jt < 16; ++jt) {
        __syncthreads();   // the ONE barrier per tile
        const int cur = jt & 1;

        if (jt < 15) {
            *(uint4*)&Ks[cur ^ 1][so0] = k0;
            *(uint4*)&Ks[cur ^ 1][so1] = k1;
            *(uint4*)&Vt[cur ^ 1][so0] = v0;
            *(uint4*)&Vt[cur ^ 1][so1] = v1;
        }
        if (jt < 14) {
            const int j2 = (jt + 2) * 64;
            k0 = *(const uint4*)&Kb[kvbase + (size_t)(j2 + srow) * HD + sc8];
            k1 = *(const uint4*)&Kb[kvbase + (size_t)(j2 + srow + 32) * HD + sc8];
            v0 = *(const uint4*)&Vtb[kvbase + (size_t)srow * NSEQ + j2 + sc8];
            v1 = *(const uint4*)&Vtb[kvbase + (size_t)(srow + 32) * NSEQ + j2 + sc8];
            #pragma unroll
            for (int jb = 0; jb < 4; ++jb)
                pk4l[jb] = *(const uint4*)(prow + j2 + jb * 16);
        }

        // S^T = K Q^T
        f32x4 sacc[4];
        __builtin_amdgcn_s_setprio(1);
        #pragma unroll
        for (int jb = 0; jb < 4; ++jb) {
            sacc[jb] = zero;
            const bf16x8 kb0 = *(const bf16x8*)&Ks[cur][(jb * 16 + col) * 72 + quad * 8];
            const bf16x8 kb1 = *(const bf16x8*)&Ks[cur][(jb * 16 + col) * 72 + 32 + quad * 8];
            sacc[jb] = __builtin_amdgcn_mfma_f32_16x16x32_bf16(kb0, aq0, sacc[jb], 0, 0, 0);
            sacc[jb] = __builtin_amdgcn_mfma_f32_16x16x32_bf16(kb1, aq1, sacc[jb], 0, 0, 0);
        }
        __builtin_amdgcn_s_setprio(0);

        // fixed-m softmax with PREFETCHED bias: p = exp2(s + rbc)
        float psum = 0.f;
        #pragma unroll
        for (int jb = 0; jb < 4; ++jb) {
            const float p0 = exp2f(sacc[jb][0] + rbc[jb][0]);
            const float p1 = exp2f(sacc[jb][1] + rbc[jb][1]);
            const float p2 = exp2f(sacc[jb][2] + rbc[jb][2]);
            const float p3 = exp2f(sacc[jb][3] + rbc[jb][3]);
            psum += (p0 + p1) + (p2 + p3);
            uint2 st;
            st.x = pk2(p0, p1);
            st.y = pk2(p2, p3);
            *(uint2*)&Ps[(w * 16 + col) * 72 + jb * 16 + quad * 4] = st;
        }
        l_l += psum;

        // O += P V; next-tile bias gathers interleaved with the PV MFMAs
        const bf16x8 ap0 = *(const bf16x8*)&Ps[(w * 16 + col) * 72 + quad * 8];
        const bf16x8 ap1 = *(const bf16x8*)&Ps[(w * 16 + col) * 72 + 32 + quad * 8];
        __builtin_amdgcn_s_setprio(1);
        #pragma unroll
        for (int db = 0; db < 4; ++db) {
            const bf16x8 vv0 = *(const bf16x8*)&Vt[cur][(db * 16 + col) * 72 + quad * 8];
            const bf16x8 vv1 = *(const bf16x8*)&Vt[cur][(db * 16 + col) * 72 + 32 + quad * 8];
            o_acc[db] = __builtin_amdgcn_mfma_f32_16x16x32_bf16(ap0, vv0, o_acc[db], 0, 0, 0);
            o_acc[db] = __builtin_amdgcn_mfma_f32_16x16x32_bf16(ap1, vv1, o_acc[db], 0, 0, 0);
            if (jt < 15) {
                const uint4 pkv = pk4g[db];
                rbn[db][0] = RBIAS(pkv.x);
                rbn[db][1] = RBIAS(pkv.y);
                rbn[db][2] = RBIAS(pkv.z);
                rbn[db][3] = RBIAS(pkv.w);
            }
        }
        __builtin_amdgcn_s_setprio(0);

        // rotate pipeline regs (renamed away by the unroll)
        #pragma unroll
        for (int jb = 0; jb < 4; ++jb) {
            pk4g[jb] = pk4l[jb];
            rbc[jb][0] = rbn[jb][0];
            rbc[jb][1] = rbn[jb][1];
            rbc[jb][2] = rbn[jb][2];
            rbc[jb][3] = rbn[jb][3];
        }
    }

    // epilogue: reduce l over quads, normalize, store bf16
    float l = l_l;
    l += __shfl_xor(l, 16);
    l += __shfl_xor(l, 32);
    #pragma unroll
    for (int r = 0; r < 4; ++r) {
        const float lr = __shfl(l, w * 16 + quad * 4 + r);
        const float inv = 1.f / lr;
        const int ri = w * 16 + quad * 4 + r;
        const size_t base = ((size_t)(b * NSEQ) + i0 + ri) * DMODEL + h * HD;
        #pragma unroll
        for (int db = 0; db < 4; ++db)
            Ob[base + db * 16 + col] = f2bf(o_acc[db][r] * inv);
    }
}

// ---------------------------------------------------------------------------
// Proj GEMM (bf16 MFMA), unchanged: 64x64 tiles, BK=32, global_load_lds.
// ---------------------------------------------------------------------------
__global__ __launch_bounds__(256) void proj_gemm(
    const ushort_t* __restrict__ A, const ushort_t* __restrict__ B,
    const float* __restrict__ bias, float* __restrict__ out)
{
    __shared__ __align__(16) ushort_t As[64 * 32];
    __shared__ __align__(16) ushort_t Bs[64 * 32];
    const int t = threadIdx.x;
    const int lane = t & 63, w = t >> 6;
    const int wr = w >> 1, wc = w & 1;
    const int col = lane & 15, quad = lane >> 4;
    const int m0 = blockIdx.y * 64, c0 = blockIdx.x * 64;

    const f32x4 zero = {0.f, 0.f, 0.f, 0.f};
    f32x4 acc[2][2];
    #pragma unroll
    for (int i = 0; i < 2; ++i)
        #pragma unroll
        for (int j = 0; j < 2; ++j) acc[i][j] = zero;

    const int srow = w * 16 + (lane >> 2);
    const int scol = (lane & 3) * 8;
    const ushort_t* Ag = A + (size_t)(m0 + srow) * DMODEL + scol;
    const ushort_t* Bg = B + (size_t)(c0 + srow) * DMODEL + scol;
    ushort_t* Asw = &As[w * 16 * 32];
    ushort_t* Bsw = &Bs[w * 16 * 32];

    for (int k0 = 0; k0 < DMODEL; k0 += 32) {
        __syncthreads();
        gl_lds16(Ag + k0, Asw);
        gl_lds16(Bg + k0, Bsw);
        __syncthreads();
        bf16x8 af[2], bf[2];
        #pragma unroll
        for (int im = 0; im < 2; ++im)
            af[im] = *(const bf16x8*)&As[(wr * 32 + im * 16 + col) * 32 + quad * 8];
        #pragma unroll
        for (int jn = 0; jn < 2; ++jn)
            bf[jn] = *(const bf16x8*)&Bs[(wc * 32 + jn * 16 + col) * 32 + quad * 8];
        #pragma unroll
        for (int im = 0; im < 2; ++im)
            #pragma unroll
            for (int jn = 0; jn < 2; ++jn)
                acc[im][jn] = __builtin_amdgcn_mfma_f32_16x16x32_bf16(af[im], bf[jn], acc[im][jn], 0, 0, 0);
    }

    #pragma unroll
    for (int im = 0; im < 2; ++im) {
        #pragma unroll
        for (int jn = 0; jn < 2; ++jn) {
            const int c = c0 + wc * 32 + jn * 16 + col;
            const float bv = bias[c];
            #pragma unroll
            for (int r = 0; r < 4; ++r) {
                const int m = m0 + wr * 32 + im * 16 + quad * 4 + r;
                out[(size_t)m * DMODEL + c] = acc[im][jn][r] + bv;
            }
        }
    }
}

extern "C" void kernel_launch(void* const* d_in, const int* in_sizes, int n_in,
                              void* d_out, int out_size, void* d_ws, size_t ws_size,
                              hipStream_t stream) {
    const float* x       = (const float*)d_in[0];
    const float* coords  = (const float*)d_in[1];
    const float* elev    = (const float*)d_in[2];
    const float* qkv_w   = (const float*)d_in[3];
    const float* qkv_b   = (const float*)d_in[4];
    const float* proj_w  = (const float*)d_in[5];
    const float* proj_b  = (const float*)d_in[6];
    const float* btable  = (const float*)d_in[7];
    const float* alpha   = (const float*)d_in[8];
    float* out = (float*)d_out;

    ushort_t* wsu = (ushort_t*)d_ws;
    ushort_t* xb  = wsu;
    ushort_t* wqb = wsu + 3145728;
    ushort_t* pwb = wsu + 4915200;
    ushort_t* Qb  = wsu + 5505024;
    ushort_t* Kb  = wsu + 8650752;
    ushort_t* Vtb = wsu + 11796480;
    ushort_t* Ob  = wsu + 14942208;
    unsigned* pck = (unsigned*)(wsu + 18087936);   // 4M uint32 = 16 MB

    prep_kernel<<<CVT_BLOCKS, 256, 0, stream>>>(x, qkv_w, proj_w, wsu);
    qkv_gemm<<<QKV_BLOCKS + 4096, 256, 0, stream>>>(
        xb, wqb, qkv_b, Qb, Kb, Vtb, coords, elev, alpha, pck);
    attn_mfma<<<768, 256, 0, stream>>>(Qb, Kb, Vtb, pck, btable, Ob);
    proj_gemm<<<dim3(12, 64), 256, 0, stream>>>(Ob, pwb, proj_b, out);
}

// Round 7
// 170.141 us; speedup vs baseline: 1.1760x; 1.0738x over previous
//
#include <hip/hip_runtime.h>
#include <hip/hip_bf16.h>
#include <math.h>

#define NH 12
#define HD 64
#define NSEQ 1024
#define DMODEL 768
#define LOG2E 1.44269504f

typedef unsigned short ushort_t;
typedef float f32x4 __attribute__((ext_vector_type(4)));
typedef short bf16x8 __attribute__((ext_vector_type(8)));

__device__ __forceinline__ ushort_t f2bf(float f) {
    unsigned int u = __float_as_uint(f);
    u += 0x7FFFu + ((u >> 16) & 1u);   // RNE
    return (ushort_t)(u >> 16);
}

__device__ __forceinline__ unsigned pk2(float x, float y) {
    __hip_bfloat162 t = __float22bfloat162_rn(make_float2(x, y));
    union { __hip_bfloat162 b; unsigned u; } c; c.b = t;
    return c.u;
}

// async global->LDS DMA, 16B per lane; LDS dest = wave-uniform base + lane*16
__device__ __forceinline__ void gl_lds16(const ushort_t* g, ushort_t* l) {
    __builtin_amdgcn_global_load_lds(
        (const __attribute__((address_space(1))) unsigned int*)g,
        (__attribute__((address_space(3))) unsigned int*)l, 16, 0, 0);
}

// ---------------------------------------------------------------------------
// prep kernel (x + qkv_w cvt only): proj_w cvt moved to qkv tail blocks.
// ---------------------------------------------------------------------------
#define XB_N   3145728u
#define WQB_N  1769472u
#define PWB_N  589824u
#define CVT_BLOCKS 2400

__global__ __launch_bounds__(256) void prep_kernel(
    const float* __restrict__ x, const float* __restrict__ w1,
    ushort_t* __restrict__ dst)
{
    const int t = threadIdx.x;
    const unsigned i = blockIdx.x * 256 + t;      // 8-elem chunk id
    const unsigned n0 = XB_N / 8, n1 = n0 + WQB_N / 8;
    if (i >= n1) return;
    const float* src; unsigned off;
    if (i < n0) { src = x;  off = i; }
    else        { src = w1; off = i - n0; }
    const float4 a = ((const float4*)src)[off * 2];
    const float4 b = ((const float4*)src)[off * 2 + 1];
    uint4 pk;
    pk.x = pk2(a.x, a.y); pk.y = pk2(a.z, a.w);
    pk.z = pk2(b.x, b.y); pk.w = pk2(b.z, b.w);
    ((uint4*)dst)[i] = pk;
}

__device__ __forceinline__ int bucketf(int rel) {
    const int n = -rel;
    const int u = (n < 0) ? 16 : 0;
    const int a = n < 0 ? -n : n;
    if (a < 8) return u + a;
    int v = 8 + (int)(log2f((float)a * 0.125f) * 2.0f + 1e-4f);
    if (v > 15) v = 15;
    return u + v;
}

// ---------------------------------------------------------------------------
// QKV GEMM, R7: 128x128 tiles, BK=64 (12 iters, half the barrier drains of
// BK=32). LDS [128][64] per matrix, XOR-swizzled (rule-21 both-sides):
// linear gl_lds dest + pre-swizzled global source colgroup^=(row&7) +
// matching XOR on the ds_read_b128 fragment address (bank-BW-minimal).
// Grid: [0,576) GEMM (XCD-swizzled); [576,4672) bias-pack; [4672,4960)
// proj_w fp32->bf16 cvt (needed 2 kernels later).
// ---------------------------------------------------------------------------
#define QKV_BLOCKS 576
#define PACK_BLOCKS 4096
#define PW_BLOCKS 288

__global__ __launch_bounds__(256) void qkv_gemm(
    const ushort_t* __restrict__ A, const ushort_t* __restrict__ B,
    const float* __restrict__ bias,
    ushort_t* __restrict__ Qb, ushort_t* __restrict__ Kb, ushort_t* __restrict__ Vtb,
    const float* __restrict__ coords, const float* __restrict__ elev,
    const float* __restrict__ alpha_p, unsigned* __restrict__ pack,
    const float* __restrict__ pw, ushort_t* __restrict__ pwb)
{
    __shared__ __align__(16) ushort_t SM[16384];   // As [128][64], Bs [128][64]
    const int t = threadIdx.x;

    if (blockIdx.x >= QKV_BLOCKS + PACK_BLOCKS) {
        // ---- proj_w conversion tail ----
        const unsigned i = (blockIdx.x - QKV_BLOCKS - PACK_BLOCKS) * 256 + t;
        if (i >= PWB_N / 8) return;
        const float4 a = ((const float4*)pw)[i * 2];
        const float4 b = ((const float4*)pw)[i * 2 + 1];
        uint4 pk;
        pk.x = pk2(a.x, a.y); pk.y = pk2(a.z, a.w);
        pk.z = pk2(b.x, b.y); pk.w = pk2(b.z, b.w);
        ((uint4*)pwb)[i] = pk;
        return;
    }
    if (blockIdx.x >= QKV_BLOCKS) {
        // ---- bias-pack half ----
        const int blk = blockIdx.x - QKV_BLOCKS;
        const int b = blk >> 10, i = blk & 1023;
        const float alpha = alpha_p[0];
        const float2 ci = *(const float2*)&coords[(size_t)(b * NSEQ + i) * 2];
        const int cxi = (int)(ci.x * 128.0f), cyi = (int)(ci.y * 128.0f);
        const float ei = elev[b * NSEQ + i];
        const int j0 = t * 4;
        const float4 c01 = *(const float4*)&coords[(size_t)(b * NSEQ + j0) * 2];
        const float4 c23 = *(const float4*)&coords[(size_t)(b * NSEQ + j0 + 2) * 2];
        const float4 ej4 = *(const float4*)&elev[b * NSEQ + j0];
        const float cjx[4] = {c01.x, c01.z, c23.x, c23.z};
        const float cjy[4] = {c01.y, c01.w, c23.y, c23.w};
        const float ejv[4] = {ej4.x, ej4.y, ej4.z, ej4.w};
        unsigned r[4];
        #pragma unroll
        for (int k = 0; k < 4; ++k) {
            const int bx = bucketf(cxi - (int)(cjx[k] * 128.0f));
            const int by = bucketf(cyi - (int)(cjy[k] * 128.0f));
            const int idx = (bx << 5) + by;
            const float ed = (ejv[k] - ei) * 1e-3f;
            const float eb = fmaxf(-alpha * fmaxf(ed, 0.0f), -10.0f) * LOG2E;
            r[k] = ((unsigned)f2bf(eb) << 16) | (unsigned)idx;
        }
        uint4 o; o.x = r[0]; o.y = r[1]; o.z = r[2]; o.w = r[3];
        *(uint4*)&pack[((size_t)b << 20) + (size_t)i * NSEQ + j0] = o;
        return;
    }

    // ---- GEMM half ----
    // XCD swizzle: 576 = 8 XCDs x 72; each XCD owns 4 complete M-panels.
    const int lid = (blockIdx.x & 7) * 72 + (blockIdx.x >> 3);
    const int bx = lid % 18, by = lid / 18;
    const int m0 = by * 128, c0 = bx * 128;

    ushort_t* Asb = SM;
    ushort_t* Bsb = SM + 8192;
    const int lane = t & 63, w = t >> 6;
    const int wr = w >> 1, wc = w & 1;            // wave quadrant: 64M x 64N
    const int col = lane & 15, quad = lane >> 4;
    const int c7 = col & 7;

    const f32x4 zero = {0.f, 0.f, 0.f, 0.f};
    f32x4 acc[4][4];
    #pragma unroll
    for (int i = 0; i < 4; ++i)
        #pragma unroll
        for (int j = 0; j < 4; ++j) acc[i][j] = zero;

    // staging: wave w stages rows w*32..w*32+31 of A and B (4 gl_lds each).
    // source col pre-swizzled so LDS (row, g) holds global group g^(row&7).
    const int r8 = lane >> 3, g8 = lane & 7;
    const int gsw = ((g8 ^ r8) * 8);
    const ushort_t* Ag = A + (size_t)(m0 + w * 32 + r8) * DMODEL + gsw;
    const ushort_t* Bg = B + (size_t)(c0 + w * 32 + r8) * DMODEL + gsw;
    ushort_t* Asw = Asb + (w * 32) * 64;
    ushort_t* Bsw = Bsb + (w * 32) * 64;

    for (int k0 = 0; k0 < DMODEL; k0 += 64) {
        __syncthreads();
        gl_lds16(Ag + k0, Asw);
        gl_lds16(Ag + (size_t)8 * DMODEL + k0, Asw + 8 * 64);
        gl_lds16(Ag + (size_t)16 * DMODEL + k0, Asw + 16 * 64);
        gl_lds16(Ag + (size_t)24 * DMODEL + k0, Asw + 24 * 64);
        gl_lds16(Bg + k0, Bsw);
        gl_lds16(Bg + (size_t)8 * DMODEL + k0, Bsw + 8 * 64);
        gl_lds16(Bg + (size_t)16 * DMODEL + k0, Bsw + 16 * 64);
        gl_lds16(Bg + (size_t)24 * DMODEL + k0, Bsw + 24 * 64);
        __syncthreads();   // compiler drains vmcnt here (once per 64-K step)
        #pragma unroll
        for (int kk = 0; kk < 2; ++kk) {
            bf16x8 af[4], bf[4];
            #pragma unroll
            for (int im = 0; im < 4; ++im)
                af[im] = *(const bf16x8*)&Asb[(wr * 64 + im * 16 + col) * 64
                        + ((4 * kk + quad) ^ c7) * 8];
            #pragma unroll
            for (int jn = 0; jn < 4; ++jn)
                bf[jn] = *(const bf16x8*)&Bsb[(wc * 64 + jn * 16 + col) * 64
                        + ((4 * kk + quad) ^ c7) * 8];
            #pragma unroll
            for (int im = 0; im < 4; ++im)
                #pragma unroll
                for (int jn = 0; jn < 4; ++jn)
                    acc[im][jn] = __builtin_amdgcn_mfma_f32_16x16x32_bf16(af[im], bf[jn], acc[im][jn], 0, 0, 0);
        }
    }

    const int cbw = c0 + wc * 64;                 // wave's 64-col base = one head
    const int s = cbw / DMODEL;                   // wave-uniform
    const int h = (cbw % DMODEL) >> 6;
    const int b = m0 >> 10;
    const int bh = b * NH + h;
    const int n0 = (m0 & (NSEQ - 1)) + wr * 64;

    float bv[4];
    #pragma unroll
    for (int jn = 0; jn < 4; ++jn) bv[jn] = bias[cbw + jn * 16 + col];

    __syncthreads();   // retire all MFMA fragment reads before LDS reuse

    if (s < 2) {
        // LDS transpose epilogue: per im-block the wave writes a 16x64 bf16
        // tile (stride 72), reads rows back, stores 2 coalesced uint4/lane.
        ushort_t* lt = SM + w * 1152;             // 16 rows x 72
        ushort_t* dst = (s == 0) ? Qb : Kb;
        const float sc = (s == 0) ? 0.125f * LOG2E : 1.0f;
        const int row16 = lane >> 2, seg = lane & 3;
        #pragma unroll
        for (int im = 0; im < 4; ++im) {
            #pragma unroll
            for (int jn = 0; jn < 4; ++jn) {
                const f32x4 a = acc[im][jn];
                #pragma unroll
                for (int r = 0; r < 4; ++r)
                    lt[(quad * 4 + r) * 72 + jn * 16 + col] = f2bf((a[r] + bv[jn]) * sc);
            }
            // same-wave DS is in-order: reads below see the writes above
            const uint4 u0 = *(const uint4*)&lt[row16 * 72 + seg * 8];
            const uint4 u1 = *(const uint4*)&lt[row16 * 72 + 32 + seg * 8];
            const size_t gb = ((size_t)bh * NSEQ + n0 + im * 16 + row16) * HD
                            + seg * 8;
            *(uint4*)&dst[gb] = u0;
            *(uint4*)&dst[gb + 32] = u1;
        }
    } else {
        #pragma unroll
        for (int im = 0; im < 4; ++im) {
            #pragma unroll
            for (int jn = 0; jn < 4; ++jn) {
                const int d = jn * 16 + col;
                const float bvv = bv[jn];
                const f32x4 a = acc[im][jn];
                uint2 p;
                p.x = pk2(a[0] + bvv, a[1] + bvv);
                p.y = pk2(a[2] + bvv, a[3] + bvv);
                *(uint2*)&Vtb[((size_t)bh * HD + d) * NSEQ + n0 + im * 16 + quad * 4] = p;
            }
        }
    }
}

// ---------------------------------------------------------------------------
// Fused flash attention (R4 best, unchanged): 256 thr, Ps via LDS, bias
// prefetch pipeline, setprio around MFMA clusters, bijective XCD swizzle.
// ---------------------------------------------------------------------------
#define RBIAS(u) (__uint_as_float((unsigned)tabu[(u) & 1023u] << 16) \
                + __uint_as_float((u) & 0xFFFF0000u))

__global__ __launch_bounds__(256) void attn_mfma(
    const ushort_t* __restrict__ Qb, const ushort_t* __restrict__ Kb,
    const ushort_t* __restrict__ Vtb,
    const unsigned* __restrict__ pack,
    const float* __restrict__ table,
    ushort_t* __restrict__ Ob)
{
    __shared__ __align__(16) ushort_t Ks[2][64 * 72];
    __shared__ __align__(16) ushort_t Vt[2][64 * 72];
    __shared__ __align__(16) ushort_t Ps[64 * 72];
    __shared__ ushort_t tabu[1024];   // bf16(table[:,h] * log2e)

    const int t = threadIdx.x;
    const int lane = t & 63, w = t >> 6;
    const int col = lane & 15, quad = lane >> 4;
    const int bid = (blockIdx.x & 7) * 96 + (blockIdx.x >> 3);   // XCD swizzle
    const int it = bid & 15, bh = bid >> 4;
    const int h = bh % NH, b = bh / NH;
    const int i0 = it * 64;

    for (int i = t; i < 1024; i += 256)
        tabu[i] = f2bf(table[i * NH + h] * LOG2E);

    const ushort_t* Qg = Qb + ((size_t)bh * NSEQ + i0 + w * 16 + col) * HD;
    const bf16x8 aq0 = *(const bf16x8*)(Qg + quad * 8);
    const bf16x8 aq1 = *(const bf16x8*)(Qg + 32 + quad * 8);

    const size_t kvbase = (size_t)bh * NSEQ * HD;
    const unsigned* prow = pack + ((size_t)b << 20)
                         + (size_t)(i0 + w * 16 + col) * NSEQ + quad * 4;

    const int srow = t >> 3, sc8 = (t & 7) * 8;
    const int so0 = srow * 72 + sc8;
    const int so1 = (srow + 32) * 72 + sc8;

    uint4 k0 = *(const uint4*)&Kb[kvbase + (size_t)srow * HD + sc8];
    uint4 k1 = *(const uint4*)&Kb[kvbase + (size_t)(srow + 32) * HD + sc8];
    uint4 v0 = *(const uint4*)&Vtb[kvbase + (size_t)srow * NSEQ + sc8];
    uint4 v1 = *(const uint4*)&Vtb[kvbase + (size_t)(srow + 32) * NSEQ + sc8];
    *(uint4*)&Ks[0][so0] = k0;
    *(uint4*)&Ks[0][so1] = k1;
    *(uint4*)&Vt[0][so0] = v0;
    *(uint4*)&Vt[0][so1] = v1;
    k0 = *(const uint4*)&Kb[kvbase + (size_t)(64 + srow) * HD + sc8];
    k1 = *(const uint4*)&Kb[kvbase + (size_t)(64 + srow + 32) * HD + sc8];
    v0 = *(const uint4*)&Vtb[kvbase + (size_t)srow * NSEQ + 64 + sc8];
    v1 = *(const uint4*)&Vtb[kvbase + (size_t)(srow + 32) * NSEQ + 64 + sc8];

    // bias pipeline: pk4g = pack words for the tile to gather next;
    // pk4l = loads in flight two tiles ahead; rbc = bias for current tile.
    uint4 pk4g[4], pk4l[4];
    #pragma unroll
    for (int jb = 0; jb < 4; ++jb)
        pk4g[jb] = *(const uint4*)(prow + jb * 16);

    __syncthreads();   // tabu (and buf0 staging) visible

    float rbc[4][4], rbn[4][4];
    #pragma unroll
    for (int jb = 0; jb < 4; ++jb) {
        const uint4 pkv = pk4g[jb];
        rbc[jb][0] = RBIAS(pkv.x);
        rbc[jb][1] = RBIAS(pkv.y);
        rbc[jb][2] = RBIAS(pkv.z);
        rbc[jb][3] = RBIAS(pkv.w);
    }
    #pragma unroll
    for (int jb = 0; jb < 4; ++jb)
        pk4g[jb] = *(const uint4*)(prow + 64 + jb * 16);

    const f32x4 zero = {0.f, 0.f, 0.f, 0.f};
    f32x4 o_acc[4];
    #pragma unroll
    for (int i = 0; i < 4; ++i) o_acc[i] = zero;
    float l_l = 0.f;

    #pragma unroll 2
    for (int jt = 0; jt < 16; ++jt) {
        __syncthreads();   // the ONE barrier per tile
        const int cur = jt & 1;

        if (jt < 15) {
            *(uint4*)&Ks[cur ^ 1][so0] = k0;
            *(uint4*)&Ks[cur ^ 1][so1] = k1;
            *(uint4*)&Vt[cur ^ 1][so0] = v0;
            *(uint4*)&Vt[cur ^ 1][so1] = v1;
        }
        if (jt < 14) {
            const int j2 = (jt + 2) * 64;
            k0 = *(const uint4*)&Kb[kvbase + (size_t)(j2 + srow) * HD + sc8];
            k1 = *(const uint4*)&Kb[kvbase + (size_t)(j2 + srow + 32) * HD + sc8];
            v0 = *(const uint4*)&Vtb[kvbase + (size_t)srow * NSEQ + j2 + sc8];
            v1 = *(const uint4*)&Vtb[kvbase + (size_t)(srow + 32) * NSEQ + j2 + sc8];
            #pragma unroll
            for (int jb = 0; jb < 4; ++jb)
                pk4l[jb] = *(const uint4*)(prow + j2 + jb * 16);
        }

        // S^T = K Q^T
        f32x4 sacc[4];
        __builtin_amdgcn_s_setprio(1);
        #pragma unroll
        for (int jb = 0; jb < 4; ++jb) {
            sacc[jb] = zero;
            const bf16x8 kb0 = *(const bf16x8*)&Ks[cur][(jb * 16 + col) * 72 + quad * 8];
            const bf16x8 kb1 = *(const bf16x8*)&Ks[cur][(jb * 16 + col) * 72 + 32 + quad * 8];
            sacc[jb] = __builtin_amdgcn_mfma_f32_16x16x32_bf16(kb0, aq0, sacc[jb], 0, 0, 0);
            sacc[jb] = __builtin_amdgcn_mfma_f32_16x16x32_bf16(kb1, aq1, sacc[jb], 0, 0, 0);
        }
        __builtin_amdgcn_s_setprio(0);

        // fixed-m softmax with PREFETCHED bias: p = exp2(s + rbc)
        float psum = 0.f;
        #pragma unroll
        for (int jb = 0; jb < 4; ++jb) {
            const float p0 = exp2f(sacc[jb][0] + rbc[jb][0]);
            const float p1 = exp2f(sacc[jb][1] + rbc[jb][1]);
            const float p2 = exp2f(sacc[jb][2] + rbc[jb][2]);
            const float p3 = exp2f(sacc[jb][3] + rbc[jb][3]);
            psum += (p0 + p1) + (p2 + p3);
            uint2 st;
            st.x = pk2(p0, p1);
            st.y = pk2(p2, p3);
            *(uint2*)&Ps[(w * 16 + col) * 72 + jb * 16 + quad * 4] = st;
        }
        l_l += psum;

        // O += P V; next-tile bias gathers interleaved with the PV MFMAs
        const bf16x8 ap0 = *(const bf16x8*)&Ps[(w * 16 + col) * 72 + quad * 8];
        const bf16x8 ap1 = *(const bf16x8*)&Ps[(w * 16 + col) * 72 + 32 + quad * 8];
        __builtin_amdgcn_s_setprio(1);
        #pragma unroll
        for (int db = 0; db < 4; ++db) {
            const bf16x8 vv0 = *(const bf16x8*)&Vt[cur][(db * 16 + col) * 72 + quad * 8];
            const bf16x8 vv1 = *(const bf16x8*)&Vt[cur][(db * 16 + col) * 72 + 32 + quad * 8];
            o_acc[db] = __builtin_amdgcn_mfma_f32_16x16x32_bf16(ap0, vv0, o_acc[db], 0, 0, 0);
            o_acc[db] = __builtin_amdgcn_mfma_f32_16x16x32_bf16(ap1, vv1, o_acc[db], 0, 0, 0);
            if (jt < 15) {
                const uint4 pkv = pk4g[db];
                rbn[db][0] = RBIAS(pkv.x);
                rbn[db][1] = RBIAS(pkv.y);
                rbn[db][2] = RBIAS(pkv.z);
                rbn[db][3] = RBIAS(pkv.w);
            }
        }
        __builtin_amdgcn_s_setprio(0);

        // rotate pipeline regs (renamed away by the unroll)
        #pragma unroll
        for (int jb = 0; jb < 4; ++jb) {
            pk4g[jb] = pk4l[jb];
            rbc[jb][0] = rbn[jb][0];
            rbc[jb][1] = rbn[jb][1];
            rbc[jb][2] = rbn[jb][2];
            rbc[jb][3] = rbn[jb][3];
        }
    }

    // epilogue: reduce l over quads, normalize, store bf16
    float l = l_l;
    l += __shfl_xor(l, 16);
    l += __shfl_xor(l, 32);
    #pragma unroll
    for (int r = 0; r < 4; ++r) {
        const float lr = __shfl(l, w * 16 + quad * 4 + r);
        const float inv = 1.f / lr;
        const int ri = w * 16 + quad * 4 + r;
        const size_t base = ((size_t)(b * NSEQ) + i0 + ri) * DMODEL + h * HD;
        #pragma unroll
        for (int db = 0; db < 4; ++db)
            Ob[base + db * 16 + col] = f2bf(o_acc[db][r] * inv);
    }
}

// ---------------------------------------------------------------------------
// Proj GEMM, R7: 64x64 tiles, BK=64 (12 iters, half the barrier drains).
// Same both-sides XOR swizzle as qkv_gemm.
// ---------------------------------------------------------------------------
__global__ __launch_bounds__(256) void proj_gemm(
    const ushort_t* __restrict__ A, const ushort_t* __restrict__ B,
    const float* __restrict__ bias, float* __restrict__ out)
{
    __shared__ __align__(16) ushort_t As[64 * 64];
    __shared__ __align__(16) ushort_t Bs[64 * 64];
    const int t = threadIdx.x;
    const int lane = t & 63, w = t >> 6;
    const int wr = w >> 1, wc = w & 1;
    const int col = lane & 15, quad = lane >> 4;
    const int c7 = col & 7;
    const int m0 = blockIdx.y * 64, c0 = blockIdx.x * 64;

    const f32x4 zero = {0.f, 0.f, 0.f, 0.f};
    f32x4 acc[2][2];
    #pragma unroll
    for (int i = 0; i < 2; ++i)
        #pragma unroll
        for (int j = 0; j < 2; ++j) acc[i][j] = zero;

    const int r8 = lane >> 3, g8 = lane & 7;
    const int gsw = ((g8 ^ r8) * 8);
    const ushort_t* Ag = A + (size_t)(m0 + w * 16 + r8) * DMODEL + gsw;
    const ushort_t* Bg = B + (size_t)(c0 + w * 16 + r8) * DMODEL + gsw;
    ushort_t* Asw = &As[(w * 16) * 64];
    ushort_t* Bsw = &Bs[(w * 16) * 64];

    for (int k0 = 0; k0 < DMODEL; k0 += 64) {
        __syncthreads();
        gl_lds16(Ag + k0, Asw);
        gl_lds16(Ag + (size_t)8 * DMODEL + k0, Asw + 8 * 64);
        gl_lds16(Bg + k0, Bsw);
        gl_lds16(Bg + (size_t)8 * DMODEL + k0, Bsw + 8 * 64);
        __syncthreads();
        #pragma unroll
        for (int kk = 0; kk < 2; ++kk) {
            bf16x8 af[2], bf[2];
            #pragma unroll
            for (int im = 0; im < 2; ++im)
                af[im] = *(const bf16x8*)&As[(wr * 32 + im * 16 + col) * 64
                        + ((4 * kk + quad) ^ c7) * 8];
            #pragma unroll
            for (int jn = 0; jn < 2; ++jn)
                bf[jn] = *(const bf16x8*)&Bs[(wc * 32 + jn * 16 + col) * 64
                        + ((4 * kk + quad) ^ c7) * 8];
            #pragma unroll
            for (int im = 0; im < 2; ++im)
                #pragma unroll
                for (int jn = 0; jn < 2; ++jn)
                    acc[im][jn] = __builtin_amdgcn_mfma_f32_16x16x32_bf16(af[im], bf[jn], acc[im][jn], 0, 0, 0);
        }
    }

    #pragma unroll
    for (int im = 0; im < 2; ++im) {
        #pragma unroll
        for (int jn = 0; jn < 2; ++jn) {
            const int c = c0 + wc * 32 + jn * 16 + col;
            const float bv = bias[c];
            #pragma unroll
            for (int r = 0; r < 4; ++r) {
                const int m = m0 + wr * 32 + im * 16 + quad * 4 + r;
                out[(size_t)m * DMODEL + c] = acc[im][jn][r] + bv;
            }
        }
    }
}

extern "C" void kernel_launch(void* const* d_in, const int* in_sizes, int n_in,
                              void* d_out, int out_size, void* d_ws, size_t ws_size,
                              hipStream_t stream) {
    const float* x       = (const float*)d_in[0];
    const float* coords  = (const float*)d_in[1];
    const float* elev    = (const float*)d_in[2];
    const float* qkv_w   = (const float*)d_in[3];
    const float* qkv_b   = (const float*)d_in[4];
    const float* proj_w  = (const float*)d_in[5];
    const float* proj_b  = (const float*)d_in[6];
    const float* btable  = (const float*)d_in[7];
    const float* alpha   = (const float*)d_in[8];
    float* out = (float*)d_out;

    ushort_t* wsu = (ushort_t*)d_ws;
    ushort_t* xb  = wsu;
    ushort_t* wqb = wsu + 3145728;
    ushort_t* pwb = wsu + 4915200;
    ushort_t* Qb  = wsu + 5505024;
    ushort_t* Kb  = wsu + 8650752;
    ushort_t* Vtb = wsu + 11796480;
    ushort_t* Ob  = wsu + 14942208;
    unsigned* pck = (unsigned*)(wsu + 18087936);   // 4M uint32 = 16 MB

    prep_kernel<<<CVT_BLOCKS, 256, 0, stream>>>(x, qkv_w, wsu);
    qkv_gemm<<<QKV_BLOCKS + PACK_BLOCKS + PW_BLOCKS, 256, 0, stream>>>(
        xb, wqb, qkv_b, Qb, Kb, Vtb, coords, elev, alpha, pck, proj_w, pwb);
    attn_mfma<<<768, 256, 0, stream>>>(Qb, Kb, Vtb, pck, btable, Ob);
    proj_gemm<<<dim3(12, 64), 256, 0, stream>>>(Ob, pwb, proj_b, out);
}

// Round 8
// 168.267 us; speedup vs baseline: 1.1891x; 1.0111x over previous
//
#include <hip/hip_runtime.h>
#include <hip/hip_bf16.h>
#include <math.h>

#define NH 12
#define HD 64
#define NSEQ 1024
#define DMODEL 768
#define LOG2E 1.44269504f

typedef unsigned short ushort_t;
typedef float f32x4 __attribute__((ext_vector_type(4)));
typedef short bf16x8 __attribute__((ext_vector_type(8)));

__device__ __forceinline__ ushort_t f2bf(float f) {
    unsigned int u = __float_as_uint(f);
    u += 0x7FFFu + ((u >> 16) & 1u);   // RNE
    return (ushort_t)(u >> 16);
}

__device__ __forceinline__ unsigned pk2(float x, float y) {
    __hip_bfloat162 t = __float22bfloat162_rn(make_float2(x, y));
    union { __hip_bfloat162 b; unsigned u; } c; c.b = t;
    return c.u;
}

// async global->LDS DMA, 16B per lane; LDS dest = wave-uniform base + lane*16
__device__ __forceinline__ void gl_lds16(const ushort_t* g, ushort_t* l) {
    __builtin_amdgcn_global_load_lds(
        (const __attribute__((address_space(1))) unsigned int*)g,
        (__attribute__((address_space(3))) unsigned int*)l, 16, 0, 0);
}

// ---------------------------------------------------------------------------
// prep kernel (x + qkv_w cvt only): proj_w cvt lives in qkv tail blocks.
// ---------------------------------------------------------------------------
#define XB_N   3145728u
#define WQB_N  1769472u
#define PWB_N  589824u
#define CVT_BLOCKS 2400

__global__ __launch_bounds__(256) void prep_kernel(
    const float* __restrict__ x, const float* __restrict__ w1,
    ushort_t* __restrict__ dst)
{
    const int t = threadIdx.x;
    const unsigned i = blockIdx.x * 256 + t;      // 8-elem chunk id
    const unsigned n0 = XB_N / 8, n1 = n0 + WQB_N / 8;
    if (i >= n1) return;
    const float* src; unsigned off;
    if (i < n0) { src = x;  off = i; }
    else        { src = w1; off = i - n0; }
    const float4 a = ((const float4*)src)[off * 2];
    const float4 b = ((const float4*)src)[off * 2 + 1];
    uint4 pk;
    pk.x = pk2(a.x, a.y); pk.y = pk2(a.z, a.w);
    pk.z = pk2(b.x, b.y); pk.w = pk2(b.z, b.w);
    ((uint4*)dst)[i] = pk;
}

__device__ __forceinline__ int bucketf(int rel) {
    const int n = -rel;
    const int u = (n < 0) ? 16 : 0;
    const int a = n < 0 ? -n : n;
    if (a < 8) return u + a;
    int v = 8 + (int)(log2f((float)a * 0.125f) * 2.0f + 1e-4f);
    if (v > 15) v = 15;
    return u + v;
}

// ---------------------------------------------------------------------------
// QKV GEMM, R8: 128x128 tiles, BK=64, T3 2-phase double-buffered LDS:
// per K-step { stage(next buf) -> compute(cur buf) -> ONE barrier }.
// The compiler's automatic vmcnt(0) drain now lands AFTER the MFMA phase,
// so global-load latency hides under compute (was: stage->drain->compute,
// full latency exposed). LDS 64 KB (2 x (A16K+B16K)) -> 2 blocks/CU; GEMM
// grid is 2.25 blocks/CU and the 4096 pack blocks backfill, so no loss.
// Both-sides XOR swizzle (rule-21) retained.
// Grid: [0,576) GEMM (XCD-swizzled); [576,4672) bias-pack; [4672,4960)
// proj_w fp32->bf16 cvt.
// ---------------------------------------------------------------------------
#define QKV_BLOCKS 576
#define PACK_BLOCKS 4096
#define PW_BLOCKS 288

__global__ __launch_bounds__(256) void qkv_gemm(
    const ushort_t* __restrict__ A, const ushort_t* __restrict__ B,
    const float* __restrict__ bias,
    ushort_t* __restrict__ Qb, ushort_t* __restrict__ Kb, ushort_t* __restrict__ Vtb,
    const float* __restrict__ coords, const float* __restrict__ elev,
    const float* __restrict__ alpha_p, unsigned* __restrict__ pack,
    const float* __restrict__ pw, ushort_t* __restrict__ pwb)
{
    // dbuf layout (ushort idx): As(b) @ b*16384, Bs(b) @ b*16384 + 8192
    __shared__ __align__(16) ushort_t SM[32768];
    const int t = threadIdx.x;

    if (blockIdx.x >= QKV_BLOCKS + PACK_BLOCKS) {
        // ---- proj_w conversion tail ----
        const unsigned i = (blockIdx.x - QKV_BLOCKS - PACK_BLOCKS) * 256 + t;
        if (i >= PWB_N / 8) return;
        const float4 a = ((const float4*)pw)[i * 2];
        const float4 b = ((const float4*)pw)[i * 2 + 1];
        uint4 pk;
        pk.x = pk2(a.x, a.y); pk.y = pk2(a.z, a.w);
        pk.z = pk2(b.x, b.y); pk.w = pk2(b.z, b.w);
        ((uint4*)pwb)[i] = pk;
        return;
    }
    if (blockIdx.x >= QKV_BLOCKS) {
        // ---- bias-pack half ----
        const int blk = blockIdx.x - QKV_BLOCKS;
        const int b = blk >> 10, i = blk & 1023;
        const float alpha = alpha_p[0];
        const float2 ci = *(const float2*)&coords[(size_t)(b * NSEQ + i) * 2];
        const int cxi = (int)(ci.x * 128.0f), cyi = (int)(ci.y * 128.0f);
        const float ei = elev[b * NSEQ + i];
        const int j0 = t * 4;
        const float4 c01 = *(const float4*)&coords[(size_t)(b * NSEQ + j0) * 2];
        const float4 c23 = *(const float4*)&coords[(size_t)(b * NSEQ + j0 + 2) * 2];
        const float4 ej4 = *(const float4*)&elev[b * NSEQ + j0];
        const float cjx[4] = {c01.x, c01.z, c23.x, c23.z};
        const float cjy[4] = {c01.y, c01.w, c23.y, c23.w};
        const float ejv[4] = {ej4.x, ej4.y, ej4.z, ej4.w};
        unsigned r[4];
        #pragma unroll
        for (int k = 0; k < 4; ++k) {
            const int bx = bucketf(cxi - (int)(cjx[k] * 128.0f));
            const int by = bucketf(cyi - (int)(cjy[k] * 128.0f));
            const int idx = (bx << 5) + by;
            const float ed = (ejv[k] - ei) * 1e-3f;
            const float eb = fmaxf(-alpha * fmaxf(ed, 0.0f), -10.0f) * LOG2E;
            r[k] = ((unsigned)f2bf(eb) << 16) | (unsigned)idx;
        }
        uint4 o; o.x = r[0]; o.y = r[1]; o.z = r[2]; o.w = r[3];
        *(uint4*)&pack[((size_t)b << 20) + (size_t)i * NSEQ + j0] = o;
        return;
    }

    // ---- GEMM half ----
    // XCD swizzle: 576 = 8 XCDs x 72; each XCD owns 4 complete M-panels.
    const int lid = (blockIdx.x & 7) * 72 + (blockIdx.x >> 3);
    const int bx = lid % 18, by = lid / 18;
    const int m0 = by * 128, c0 = bx * 128;

    const int lane = t & 63, w = t >> 6;
    const int wr = w >> 1, wc = w & 1;            // wave quadrant: 64M x 64N
    const int col = lane & 15, quad = lane >> 4;
    const int c7 = col & 7;

    const f32x4 zero = {0.f, 0.f, 0.f, 0.f};
    f32x4 acc[4][4];
    #pragma unroll
    for (int i = 0; i < 4; ++i)
        #pragma unroll
        for (int j = 0; j < 4; ++j) acc[i][j] = zero;

    // staging: wave w stages rows w*32..w*32+31 of A and B (4 gl_lds each).
    // source col pre-swizzled so LDS (row, g) holds global group g^(row&7).
    const int r8 = lane >> 3, g8 = lane & 7;
    const int gsw = ((g8 ^ r8) * 8);
    const ushort_t* Ag = A + (size_t)(m0 + w * 32 + r8) * DMODEL + gsw;
    const ushort_t* Bg = B + (size_t)(c0 + w * 32 + r8) * DMODEL + gsw;
    const int wso = (w * 32) * 64;                // wave staging offset in buf

    // stage one K-step into buffer at ushort-offset bo
    auto STAGE = [&](int bo, int k0) {
        ushort_t* Aw = SM + bo + wso;
        ushort_t* Bw = SM + bo + 8192 + wso;
        gl_lds16(Ag + k0, Aw);
        gl_lds16(Ag + (size_t)8 * DMODEL + k0, Aw + 8 * 64);
        gl_lds16(Ag + (size_t)16 * DMODEL + k0, Aw + 16 * 64);
        gl_lds16(Ag + (size_t)24 * DMODEL + k0, Aw + 24 * 64);
        gl_lds16(Bg + k0, Bw);
        gl_lds16(Bg + (size_t)8 * DMODEL + k0, Bw + 8 * 64);
        gl_lds16(Bg + (size_t)16 * DMODEL + k0, Bw + 16 * 64);
        gl_lds16(Bg + (size_t)24 * DMODEL + k0, Bw + 24 * 64);
    };

    STAGE(0, 0);
    __syncthreads();   // prologue drain: buf0 ready

    #pragma unroll 2
    for (int k = 0; k < 12; ++k) {
        const int bo = (k & 1) * 16384;
        if (k < 11) STAGE(16384 - bo, (k + 1) * 64);   // issue next (no wait)
        #pragma unroll
        for (int kk = 0; kk < 2; ++kk) {
            bf16x8 af[4], bf[4];
            #pragma unroll
            for (int im = 0; im < 4; ++im)
                af[im] = *(const bf16x8*)&SM[bo + (wr * 64 + im * 16 + col) * 64
                        + ((4 * kk + quad) ^ c7) * 8];
            #pragma unroll
            for (int jn = 0; jn < 4; ++jn)
                bf[jn] = *(const bf16x8*)&SM[bo + 8192 + (wc * 64 + jn * 16 + col) * 64
                        + ((4 * kk + quad) ^ c7) * 8];
            #pragma unroll
            for (int im = 0; im < 4; ++im)
                #pragma unroll
                for (int jn = 0; jn < 4; ++jn)
                    acc[im][jn] = __builtin_amdgcn_mfma_f32_16x16x32_bf16(af[im], bf[jn], acc[im][jn], 0, 0, 0);
        }
        __syncthreads();   // ONE barrier/step; compiler's vmcnt drain lands
                           // here, AFTER compute -> load latency hidden
    }

    const int cbw = c0 + wc * 64;                 // wave's 64-col base = one head
    const int s = cbw / DMODEL;                   // wave-uniform
    const int h = (cbw % DMODEL) >> 6;
    const int b = m0 >> 10;
    const int bh = b * NH + h;
    const int n0 = (m0 & (NSEQ - 1)) + wr * 64;

    float bv[4];
    #pragma unroll
    for (int jn = 0; jn < 4; ++jn) bv[jn] = bias[cbw + jn * 16 + col];

    if (s < 2) {
        // LDS transpose epilogue: per im-block the wave writes a 16x64 bf16
        // tile (stride 72), reads rows back, stores 2 coalesced uint4/lane.
        ushort_t* lt = SM + w * 1152;             // 16 rows x 72
        ushort_t* dst = (s == 0) ? Qb : Kb;
        const float sc = (s == 0) ? 0.125f * LOG2E : 1.0f;
        const int row16 = lane >> 2, seg = lane & 3;
        #pragma unroll
        for (int im = 0; im < 4; ++im) {
            #pragma unroll
            for (int jn = 0; jn < 4; ++jn) {
                const f32x4 a = acc[im][jn];
                #pragma unroll
                for (int r = 0; r < 4; ++r)
                    lt[(quad * 4 + r) * 72 + jn * 16 + col] = f2bf((a[r] + bv[jn]) * sc);
            }
            // same-wave DS is in-order: reads below see the writes above
            const uint4 u0 = *(const uint4*)&lt[row16 * 72 + seg * 8];
            const uint4 u1 = *(const uint4*)&lt[row16 * 72 + 32 + seg * 8];
            const size_t gb = ((size_t)bh * NSEQ + n0 + im * 16 + row16) * HD
                            + seg * 8;
            *(uint4*)&dst[gb] = u0;
            *(uint4*)&dst[gb + 32] = u1;
        }
    } else {
        #pragma unroll
        for (int im = 0; im < 4; ++im) {
            #pragma unroll
            for (int jn = 0; jn < 4; ++jn) {
                const int d = jn * 16 + col;
                const float bvv = bv[jn];
                const f32x4 a = acc[im][jn];
                uint2 p;
                p.x = pk2(a[0] + bvv, a[1] + bvv);
                p.y = pk2(a[2] + bvv, a[3] + bvv);
                *(uint2*)&Vtb[((size_t)bh * HD + d) * NSEQ + n0 + im * 16 + quad * 4] = p;
            }
        }
    }
}

// ---------------------------------------------------------------------------
// Fused flash attention (R4 best, unchanged): 256 thr, Ps via LDS, bias
// prefetch pipeline, setprio around MFMA clusters, bijective XCD swizzle.
// ---------------------------------------------------------------------------
#define RBIAS(u) (__uint_as_float((unsigned)tabu[(u) & 1023u] << 16) \
                + __uint_as_float((u) & 0xFFFF0000u))

__global__ __launch_bounds__(256) void attn_mfma(
    const ushort_t* __restrict__ Qb, const ushort_t* __restrict__ Kb,
    const ushort_t* __restrict__ Vtb,
    const unsigned* __restrict__ pack,
    const float* __restrict__ table,
    ushort_t* __restrict__ Ob)
{
    __shared__ __align__(16) ushort_t Ks[2][64 * 72];
    __shared__ __align__(16) ushort_t Vt[2][64 * 72];
    __shared__ __align__(16) ushort_t Ps[64 * 72];
    __shared__ ushort_t tabu[1024];   // bf16(table[:,h] * log2e)

    const int t = threadIdx.x;
    const int lane = t & 63, w = t >> 6;
    const int col = lane & 15, quad = lane >> 4;
    const int bid = (blockIdx.x & 7) * 96 + (blockIdx.x >> 3);   // XCD swizzle
    const int it = bid & 15, bh = bid >> 4;
    const int h = bh % NH, b = bh / NH;
    const int i0 = it * 64;

    for (int i = t; i < 1024; i += 256)
        tabu[i] = f2bf(table[i * NH + h] * LOG2E);

    const ushort_t* Qg = Qb + ((size_t)bh * NSEQ + i0 + w * 16 + col) * HD;
    const bf16x8 aq0 = *(const bf16x8*)(Qg + quad * 8);
    const bf16x8 aq1 = *(const bf16x8*)(Qg + 32 + quad * 8);

    const size_t kvbase = (size_t)bh * NSEQ * HD;
    const unsigned* prow = pack + ((size_t)b << 20)
                         + (size_t)(i0 + w * 16 + col) * NSEQ + quad * 4;

    const int srow = t >> 3, sc8 = (t & 7) * 8;
    const int so0 = srow * 72 + sc8;
    const int so1 = (srow + 32) * 72 + sc8;

    uint4 k0 = *(const uint4*)&Kb[kvbase + (size_t)srow * HD + sc8];
    uint4 k1 = *(const uint4*)&Kb[kvbase + (size_t)(srow + 32) * HD + sc8];
    uint4 v0 = *(const uint4*)&Vtb[kvbase + (size_t)srow * NSEQ + sc8];
    uint4 v1 = *(const uint4*)&Vtb[kvbase + (size_t)(srow + 32) * NSEQ + sc8];
    *(uint4*)&Ks[0][so0] = k0;
    *(uint4*)&Ks[0][so1] = k1;
    *(uint4*)&Vt[0][so0] = v0;
    *(uint4*)&Vt[0][so1] = v1;
    k0 = *(const uint4*)&Kb[kvbase + (size_t)(64 + srow) * HD + sc8];
    k1 = *(const uint4*)&Kb[kvbase + (size_t)(64 + srow + 32) * HD + sc8];
    v0 = *(const uint4*)&Vtb[kvbase + (size_t)srow * NSEQ + 64 + sc8];
    v1 = *(const uint4*)&Vtb[kvbase + (size_t)(srow + 32) * NSEQ + 64 + sc8];

    // bias pipeline: pk4g = pack words for the tile to gather next;
    // pk4l = loads in flight two tiles ahead; rbc = bias for current tile.
    uint4 pk4g[4], pk4l[4];
    #pragma unroll
    for (int jb = 0; jb < 4; ++jb)
        pk4g[jb] = *(const uint4*)(prow + jb * 16);

    __syncthreads();   // tabu (and buf0 staging) visible

    float rbc[4][4], rbn[4][4];
    #pragma unroll
    for (int jb = 0; jb < 4; ++jb) {
        const uint4 pkv = pk4g[jb];
        rbc[jb][0] = RBIAS(pkv.x);
        rbc[jb][1] = RBIAS(pkv.y);
        rbc[jb][2] = RBIAS(pkv.z);
        rbc[jb][3] = RBIAS(pkv.w);
    }
    #pragma unroll
    for (int jb = 0; jb < 4; ++jb)
        pk4g[jb] = *(const uint4*)(prow + 64 + jb * 16);

    const f32x4 zero = {0.f, 0.f, 0.f, 0.f};
    f32x4 o_acc[4];
    #pragma unroll
    for (int i = 0; i < 4; ++i) o_acc[i] = zero;
    float l_l = 0.f;

    #pragma unroll 2
    for (int jt = 0; jt < 16; ++jt) {
        __syncthreads();   // the ONE barrier per tile
        const int cur = jt & 1;

        if (jt < 15) {
            *(uint4*)&Ks[cur ^ 1][so0] = k0;
            *(uint4*)&Ks[cur ^ 1][so1] = k1;
            *(uint4*)&Vt[cur ^ 1][so0] = v0;
            *(uint4*)&Vt[cur ^ 1][so1] = v1;
        }
        if (jt < 14) {
            const int j2 = (jt + 2) * 64;
            k0 = *(const uint4*)&Kb[kvbase + (size_t)(j2 + srow) * HD + sc8];
            k1 = *(const uint4*)&Kb[kvbase + (size_t)(j2 + srow + 32) * HD + sc8];
            v0 = *(const uint4*)&Vtb[kvbase + (size_t)srow * NSEQ + j2 + sc8];
            v1 = *(const uint4*)&Vtb[kvbase + (size_t)(srow + 32) * NSEQ + j2 + sc8];
            #pragma unroll
            for (int jb = 0; jb < 4; ++jb)
                pk4l[jb] = *(const uint4*)(prow + j2 + jb * 16);
        }

        // S^T = K Q^T
        f32x4 sacc[4];
        __builtin_amdgcn_s_setprio(1);
        #pragma unroll
        for (int jb = 0; jb < 4; ++jb) {
            sacc[jb] = zero;
            const bf16x8 kb0 = *(const bf16x8*)&Ks[cur][(jb * 16 + col) * 72 + quad * 8];
            const bf16x8 kb1 = *(const bf16x8*)&Ks[cur][(jb * 16 + col) * 72 + 32 + quad * 8];
            sacc[jb] = __builtin_amdgcn_mfma_f32_16x16x32_bf16(kb0, aq0, sacc[jb], 0, 0, 0);
            sacc[jb] = __builtin_amdgcn_mfma_f32_16x16x32_bf16(kb1, aq1, sacc[jb], 0, 0, 0);
        }
        __builtin_amdgcn_s_setprio(0);

        // fixed-m softmax with PREFETCHED bias: p = exp2(s + rbc)
        float psum = 0.f;
        #pragma unroll
        for (int jb = 0; jb < 4; ++jb) {
            const float p0 = exp2f(sacc[jb][0] + rbc[jb][0]);
            const float p1 = exp2f(sacc[jb][1] + rbc[jb][1]);
            const float p2 = exp2f(sacc[jb][2] + rbc[jb][2]);
            const float p3 = exp2f(sacc[jb][3] + rbc[jb][3]);
            psum += (p0 + p1) + (p2 + p3);
            uint2 st;
            st.x = pk2(p0, p1);
            st.y = pk2(p2, p3);
            *(uint2*)&Ps[(w * 16 + col) * 72 + jb * 16 + quad * 4] = st;
        }
        l_l += psum;

        // O += P V; next-tile bias gathers interleaved with the PV MFMAs
        const bf16x8 ap0 = *(const bf16x8*)&Ps[(w * 16 + col) * 72 + quad * 8];
        const bf16x8 ap1 = *(const bf16x8*)&Ps[(w * 16 + col) * 72 + 32 + quad * 8];
        __builtin_amdgcn_s_setprio(1);
        #pragma unroll
        for (int db = 0; db < 4; ++db) {
            const bf16x8 vv0 = *(const bf16x8*)&Vt[cur][(db * 16 + col) * 72 + quad * 8];
            const bf16x8 vv1 = *(const bf16x8*)&Vt[cur][(db * 16 + col) * 72 + 32 + quad * 8];
            o_acc[db] = __builtin_amdgcn_mfma_f32_16x16x32_bf16(ap0, vv0, o_acc[db], 0, 0, 0);
            o_acc[db] = __builtin_amdgcn_mfma_f32_16x16x32_bf16(ap1, vv1, o_acc[db], 0, 0, 0);
            if (jt < 15) {
                const uint4 pkv = pk4g[db];
                rbn[db][0] = RBIAS(pkv.x);
                rbn[db][1] = RBIAS(pkv.y);
                rbn[db][2] = RBIAS(pkv.z);
                rbn[db][3] = RBIAS(pkv.w);
            }
        }
        __builtin_amdgcn_s_setprio(0);

        // rotate pipeline regs (renamed away by the unroll)
        #pragma unroll
        for (int jb = 0; jb < 4; ++jb) {
            pk4g[jb] = pk4l[jb];
            rbc[jb][0] = rbn[jb][0];
            rbc[jb][1] = rbn[jb][1];
            rbc[jb][2] = rbn[jb][2];
            rbc[jb][3] = rbn[jb][3];
        }
    }

    // epilogue: reduce l over quads, normalize, store bf16
    float l = l_l;
    l += __shfl_xor(l, 16);
    l += __shfl_xor(l, 32);
    #pragma unroll
    for (int r = 0; r < 4; ++r) {
        const float lr = __shfl(l, w * 16 + quad * 4 + r);
        const float inv = 1.f / lr;
        const int ri = w * 16 + quad * 4 + r;
        const size_t base = ((size_t)(b * NSEQ) + i0 + ri) * DMODEL + h * HD;
        #pragma unroll
        for (int db = 0; db < 4; ++db)
            Ob[base + db * 16 + col] = f2bf(o_acc[db][r] * inv);
    }
}

// ---------------------------------------------------------------------------
// Proj GEMM, R8: 64x64 tiles, BK=64, same T3 2-phase double-buffered
// ordering as qkv (stage next -> compute cur -> one barrier). LDS 32 KB.
// ---------------------------------------------------------------------------
__global__ __launch_bounds__(256) void proj_gemm(
    const ushort_t* __restrict__ A, const ushort_t* __restrict__ B,
    const float* __restrict__ bias, float* __restrict__ out)
{
    // dbuf layout (ushort idx): As(b) @ b*8192, Bs(b) @ b*8192 + 4096
    __shared__ __align__(16) ushort_t SM[16384];
    const int t = threadIdx.x;
    const int lane = t & 63, w = t >> 6;
    const int wr = w >> 1, wc = w & 1;
    const int col = lane & 15, quad = lane >> 4;
    const int c7 = col & 7;
    const int m0 = blockIdx.y * 64, c0 = blockIdx.x * 64;

    const f32x4 zero = {0.f, 0.f, 0.f, 0.f};
    f32x4 acc[2][2];
    #pragma unroll
    for (int i = 0; i < 2; ++i)
        #pragma unroll
        for (int j = 0; j < 2; ++j) acc[i][j] = zero;

    const int r8 = lane >> 3, g8 = lane & 7;
    const int gsw = ((g8 ^ r8) * 8);
    const ushort_t* Ag = A + (size_t)(m0 + w * 16 + r8) * DMODEL + gsw;
    const ushort_t* Bg = B + (size_t)(c0 + w * 16 + r8) * DMODEL + gsw;
    const int wso = (w * 16) * 64;

    auto STAGE = [&](int bo, int k0) {
        ushort_t* Aw = SM + bo + wso;
        ushort_t* Bw = SM + bo + 4096 + wso;
        gl_lds16(Ag + k0, Aw);
        gl_lds16(Ag + (size_t)8 * DMODEL + k0, Aw + 8 * 64);
        gl_lds16(Bg + k0, Bw);
        gl_lds16(Bg + (size_t)8 * DMODEL + k0, Bw + 8 * 64);
    };

    STAGE(0, 0);
    __syncthreads();

    #pragma unroll 2
    for (int k = 0; k < 12; ++k) {
        const int bo = (k & 1) * 8192;
        if (k < 11) STAGE(8192 - bo, (k + 1) * 64);
        #pragma unroll
        for (int kk = 0; kk < 2; ++kk) {
            bf16x8 af[2], bf[2];
            #pragma unroll
            for (int im = 0; im < 2; ++im)
                af[im] = *(const bf16x8*)&SM[bo + (wr * 32 + im * 16 + col) * 64
                        + ((4 * kk + quad) ^ c7) * 8];
            #pragma unroll
            for (int jn = 0; jn < 2; ++jn)
                bf[jn] = *(const bf16x8*)&SM[bo + 4096 + (wc * 32 + jn * 16 + col) * 64
                        + ((4 * kk + quad) ^ c7) * 8];
            #pragma unroll
            for (int im = 0; im < 2; ++im)
                #pragma unroll
                for (int jn = 0; jn < 2; ++jn)
                    acc[im][jn] = __builtin_amdgcn_mfma_f32_16x16x32_bf16(af[im], bf[jn], acc[im][jn], 0, 0, 0);
        }
        __syncthreads();
    }

    #pragma unroll
    for (int im = 0; im < 2; ++im) {
        #pragma unroll
        for (int jn = 0; jn < 2; ++jn) {
            const int c = c0 + wc * 32 + jn * 16 + col;
            const float bv = bias[c];
            #pragma unroll
            for (int r = 0; r < 4; ++r) {
                const int m = m0 + wr * 32 + im * 16 + quad * 4 + r;
                out[(size_t)m * DMODEL + c] = acc[im][jn][r] + bv;
            }
        }
    }
}

extern "C" void kernel_launch(void* const* d_in, const int* in_sizes, int n_in,
                              void* d_out, int out_size, void* d_ws, size_t ws_size,
                              hipStream_t stream) {
    const float* x       = (const float*)d_in[0];
    const float* coords  = (const float*)d_in[1];
    const float* elev    = (const float*)d_in[2];
    const float* qkv_w   = (const float*)d_in[3];
    const float* qkv_b   = (const float*)d_in[4];
    const float* proj_w  = (const float*)d_in[5];
    const float* proj_b  = (const float*)d_in[6];
    const float* btable  = (const float*)d_in[7];
    const float* alpha   = (const float*)d_in[8];
    float* out = (float*)d_out;

    ushort_t* wsu = (ushort_t*)d_ws;
    ushort_t* xb  = wsu;
    ushort_t* wqb = wsu + 3145728;
    ushort_t* pwb = wsu + 4915200;
    ushort_t* Qb  = wsu + 5505024;
    ushort_t* Kb  = wsu + 8650752;
    ushort_t* Vtb = wsu + 11796480;
    ushort_t* Ob  = wsu + 14942208;
    unsigned* pck = (unsigned*)(wsu + 18087936);   // 4M uint32 = 16 MB

    prep_kernel<<<CVT_BLOCKS, 256, 0, stream>>>(x, qkv_w, wsu);
    qkv_gemm<<<QKV_BLOCKS + PACK_BLOCKS + PW_BLOCKS, 256, 0, stream>>>(
        xb, wqb, qkv_b, Qb, Kb, Vtb, coords, elev, alpha, pck, proj_w, pwb);
    attn_mfma<<<768, 256, 0, stream>>>(Qb, Kb, Vtb, pck, btable, Ob);
    proj_gemm<<<dim3(12, 64), 256, 0, stream>>>(Ob, pwb, proj_b, out);
}